// Round 1
// baseline (1897.780 us; speedup 1.0000x reference)
//
#include <hip/hip_runtime.h>
#include <math.h>

#define NEG_SLOPE 0.2f

// ---------------------------------------------------------------------------
// K1: per-node linear transform + attention logits + self-loop init.
//   h[n,128]      = x[n,:] @ W            (x = concat(users, items))
//   a_src[n,h]    = <h[n,h,:], att_src[h,:]>
//   a_dst[n,h]    = <h[n,h,:], att_dst[h,:]>
//   ex_self       = exp(lrelu(a_src[n,h]+a_dst[n,h]))
//   denom[n,h]    = ex_self                      (self-loop term)
//   out[n,128]    = ex_self * h[n,:]             (self-loop contribution)
// One block (128 threads = 2 waves) per node; wave w == head w.
// ---------------------------------------------------------------------------
__global__ void k_node(const float* __restrict__ users,
                       const float* __restrict__ items,
                       const float* __restrict__ W,
                       const float* __restrict__ att_src,
                       const float* __restrict__ att_dst,
                       float* __restrict__ h,
                       float* __restrict__ a_src,
                       float* __restrict__ a_dst,
                       float* __restrict__ denom,
                       float* __restrict__ out,
                       int n_users)
{
    const int node = blockIdx.x;
    const int tid  = threadIdx.x;           // 0..127 == output column
    __shared__ float xs[64];
    __shared__ float asrc_sh[2], adst_sh[2];

    const float* xrow = (node < n_users)
        ? (users + (size_t)node * 64)
        : (items + (size_t)(node - n_users) * 64);
    if (tid < 64) xs[tid] = xrow[tid];
    __syncthreads();

    float sum = 0.f;
    #pragma unroll
    for (int k = 0; k < 64; ++k)
        sum = fmaf(xs[k], W[k * 128 + tid], sum);   // coalesced per k

    h[(size_t)node * 128 + tid] = sum;

    // att_src is (H,C) flat = 128 floats; col tid maps directly.
    float vs = sum * att_src[tid];
    float vd = sum * att_dst[tid];
    #pragma unroll
    for (int off = 32; off > 0; off >>= 1) {
        vs += __shfl_down(vs, off);
        vd += __shfl_down(vd, off);
    }
    const int hd = tid >> 6;                // head == wave id
    if ((tid & 63) == 0) {
        asrc_sh[hd] = vs;  adst_sh[hd] = vd;
        a_src[node * 2 + hd] = vs;
        a_dst[node * 2 + hd] = vd;
    }
    __syncthreads();

    float logit = asrc_sh[hd] + adst_sh[hd];
    float lr    = logit > 0.f ? logit : NEG_SLOPE * logit;
    float ex    = __expf(lr);
    if ((tid & 63) == 0) denom[node * 2 + hd] = ex;
    out[(size_t)node * 128 + tid] = ex * sum;
}

// ---------------------------------------------------------------------------
// K2: one wave per edge. Unnormalized softmax accumulation:
//   ex = exp(lrelu(a_src[s,h] + a_dst[d,h]))
//   denom[d,h] += ex         (lanes 0 / 32)
//   out[d,:]   += ex * h[s,:]  (each lane: float2 of channels, 2 atomics)
// No segment-max: logits are O(1), exp is shift-invariant in the ratio.
// ---------------------------------------------------------------------------
__global__ void k_edge(const int* __restrict__ src,
                       const int* __restrict__ dst,
                       const float* __restrict__ a_src,
                       const float* __restrict__ a_dst,
                       const float* __restrict__ h,
                       float* __restrict__ denom,
                       float* __restrict__ out,
                       int nedges)
{
    const int gtid = blockIdx.x * blockDim.x + threadIdx.x;
    const int e    = gtid >> 6;
    if (e >= nedges) return;
    const int lane = threadIdx.x & 63;

    const int s = src[e];
    const int d = dst[e];
    const int hd = lane >> 5;               // lanes 0-31: head0, 32-63: head1

    float logit = a_src[s * 2 + hd] + a_dst[d * 2 + hd];
    float lr    = logit > 0.f ? logit : NEG_SLOPE * logit;
    float ex    = __expf(lr);

    if ((lane & 31) == 0) atomicAdd(&denom[d * 2 + hd], ex);

    const float2 hv = *reinterpret_cast<const float2*>(h + (size_t)s * 128 + lane * 2);
    float* op = out + (size_t)d * 128 + lane * 2;
    atomicAdd(op,     ex * hv.x);
    atomicAdd(op + 1, ex * hv.y);
}

// ---------------------------------------------------------------------------
// K3: out[i] = out[i] / (denom[i>>6] + 1e-16) + bias[i & 127]
//   (i = node*128 + head*64 + c  ->  denom index node*2+head == i>>6)
// ---------------------------------------------------------------------------
__global__ void k_norm(float* __restrict__ out,
                       const float* __restrict__ denom,
                       const float* __restrict__ bias,
                       int total)
{
    int i = blockIdx.x * blockDim.x + threadIdx.x;
    if (i >= total) return;
    out[i] = out[i] / (denom[i >> 6] + 1e-16f) + bias[i & 127];
}

extern "C" void kernel_launch(void* const* d_in, const int* in_sizes, int n_in,
                              void* d_out, int out_size, void* d_ws, size_t ws_size,
                              hipStream_t stream) {
    const int*   edge  = (const int*)  d_in[0];   // (2,E) int32
    const float* users = (const float*)d_in[1];   // (N_USERS,64) f32
    const float* items = (const float*)d_in[2];   // (N_ITEMS,64) f32
    const float* W     = (const float*)d_in[3];   // (64,128) f32
    const float* att_s = (const float*)d_in[4];   // (2,64) f32
    const float* att_d = (const float*)d_in[5];   // (2,64) f32
    const float* bias  = (const float*)d_in[6];   // (128,) f32

    const int E       = in_sizes[0] / 2;
    const int n_users = in_sizes[1] / 64;
    const int n_items = in_sizes[2] / 64;
    const int N       = n_users + n_items;

    float* out = (float*)d_out;

    // Workspace: h (N*128) | a_src (N*2) | a_dst (N*2) | denom (N*2)
    char*  ws    = (char*)d_ws;
    float* h     = (float*)ws;  ws += (size_t)N * 128 * sizeof(float);
    float* a_src = (float*)ws;  ws += (size_t)N * 2   * sizeof(float);
    float* a_dst = (float*)ws;  ws += (size_t)N * 2   * sizeof(float);
    float* denom = (float*)ws;

    k_node<<<N, 128, 0, stream>>>(users, items, W, att_s, att_d,
                                  h, a_src, a_dst, denom, out, n_users);

    const int waves_per_block = 4;                 // 256 threads
    const int blocks = (E + waves_per_block - 1) / waves_per_block;
    k_edge<<<blocks, 256, 0, stream>>>(edge, edge + E, a_src, a_dst,
                                       h, denom, out, E);

    const int total = N * 128;
    k_norm<<<(total + 255) / 256, 256, 0, stream>>>(out, denom, bias, total);
}

// Round 2
// 601.912 us; speedup vs baseline: 3.1529x; 3.1529x over previous
//
#include <hip/hip_runtime.h>
#include <math.h>

#define NEG_SLOPE 0.2f

// ---------------------------------------------------------------------------
// K1: per-node linear transform + attention logits.
//   h[n,128]   = x[n,:] @ W            (x = concat(users, items))
//   a_src[n,h] = <h[n,h,:], att_src[h,:]>
//   a_dst[n,h] = <h[n,h,:], att_dst[h,:]>
// One block (128 threads = 2 waves) per node; wave w == head w.
// ---------------------------------------------------------------------------
__global__ void k_node(const float* __restrict__ users,
                       const float* __restrict__ items,
                       const float* __restrict__ W,
                       const float* __restrict__ att_src,
                       const float* __restrict__ att_dst,
                       float* __restrict__ h,
                       float* __restrict__ a_src,
                       float* __restrict__ a_dst,
                       int n_users)
{
    const int node = blockIdx.x;
    const int tid  = threadIdx.x;           // 0..127 == output column
    __shared__ float xs[64];

    const float* xrow = (node < n_users)
        ? (users + (size_t)node * 64)
        : (items + (size_t)(node - n_users) * 64);
    if (tid < 64) xs[tid] = xrow[tid];
    __syncthreads();

    float sum = 0.f;
    #pragma unroll
    for (int k = 0; k < 64; ++k)
        sum = fmaf(xs[k], W[k * 128 + tid], sum);   // coalesced per k

    h[(size_t)node * 128 + tid] = sum;

    float vs = sum * att_src[tid];
    float vd = sum * att_dst[tid];
    #pragma unroll
    for (int off = 32; off > 0; off >>= 1) {
        vs += __shfl_down(vs, off);
        vd += __shfl_down(vd, off);
    }
    const int hd = tid >> 6;                // head == wave id
    if ((tid & 63) == 0) {
        a_src[node * 2 + hd] = vs;
        a_dst[node * 2 + hd] = vd;
    }
}

// ---------------------------------------------------------------------------
// K2: histogram of destination degrees (int atomics, cheap).
// ---------------------------------------------------------------------------
__global__ void k_hist(const int* __restrict__ dst, int* __restrict__ cnt,
                       int nedges)
{
    int i = blockIdx.x * blockDim.x + threadIdx.x;
    if (i < nedges) atomicAdd(&cnt[dst[i]], 1);
}

// ---------------------------------------------------------------------------
// K3: exclusive prefix scan of cnt -> rowptr. Single block, 1024 threads,
// shuffle-scan per wave + 16-wave-sum scan (2 barriers per 1024-chunk).
// ---------------------------------------------------------------------------
__global__ void k_scan(const int* __restrict__ cnt, int* __restrict__ rowptr,
                       int n)
{
    __shared__ int sm[17];
    __shared__ int carry_s;
    const int lane = threadIdx.x & 63;
    const int wid  = threadIdx.x >> 6;     // 0..15
    if (threadIdx.x == 0) carry_s = 0;
    __syncthreads();

    for (int base = 0; base < n; base += 1024) {
        int i = base + threadIdx.x;
        int v = (i < n) ? cnt[i] : 0;

        // wave-level inclusive scan
        int incl = v;
        #pragma unroll
        for (int off = 1; off < 64; off <<= 1) {
            int t = __shfl_up(incl, off);
            if (lane >= off) incl += t;
        }
        if (lane == 63) sm[wid] = incl;
        __syncthreads();

        if (wid == 0 && lane < 16) {
            int ws = sm[lane];
            int wincl = ws;
            #pragma unroll
            for (int off = 1; off < 16; off <<= 1) {
                int t = __shfl_up(wincl, off);
                if (lane >= off) wincl += t;
            }
            sm[lane] = wincl - ws;          // exclusive wave offset
            if (lane == 15) sm[16] = wincl; // chunk total
        }
        __syncthreads();

        int carry = carry_s;
        if (i < n) rowptr[i] = carry + sm[wid] + incl - v;  // exclusive
        __syncthreads();
        if (threadIdx.x == 0) carry_s = carry + sm[16];
        __syncthreads();
    }
}

// ---------------------------------------------------------------------------
// K4: scatter src indices into dst-grouped segments.
// atomicAdd on rowptr itself: after this kernel, rowptr[d] == exclusive END
// of segment d (== start of segment d+1). Gather reads it shifted.
// ---------------------------------------------------------------------------
__global__ void k_scatter(const int* __restrict__ src, const int* __restrict__ dst,
                          int* __restrict__ rowptr, int* __restrict__ perm_src,
                          int nedges)
{
    int i = blockIdx.x * blockDim.x + threadIdx.x;
    if (i >= nedges) return;
    int pos = atomicAdd(&rowptr[dst[i]], 1);
    perm_src[pos] = src[i];
}

// ---------------------------------------------------------------------------
// K5: gather-accumulate. One wave per destination node; lane owns a float2
// of the 128 channels (lanes 0-31 head0, 32-63 head1). No atomics.
//   acc  = ex_self * h[d]            (self loop)
//   den  = ex_self
//   for each in-edge: ex = exp(lrelu(a_src[s]+a_dst[d])); den+=ex; acc+=ex*h[s]
//   out[d] = acc/(den+1e-16) + bias
// rowptr is post-scatter: start = d ? rowptr[d-1] : 0, end = rowptr[d].
// ---------------------------------------------------------------------------
__global__ void k_gather(const int* __restrict__ rowptr,
                         const int* __restrict__ perm_src,
                         const float* __restrict__ a_src,
                         const float* __restrict__ a_dst,
                         const float* __restrict__ h,
                         const float* __restrict__ bias,
                         float* __restrict__ out,
                         int nnodes)
{
    const int d = blockIdx.x * 2 + (threadIdx.x >> 6);  // 2 nodes per block
    if (d >= nnodes) return;
    const int lane = threadIdx.x & 63;
    const int hd   = lane >> 5;            // lanes 0-31: head0, 32-63: head1

    const float adv = a_dst[d * 2 + hd];

    // self loop
    float logit = a_src[d * 2 + hd] + adv;
    float lr    = logit > 0.f ? logit : NEG_SLOPE * logit;
    float den   = __expf(lr);
    const float2 hself = *reinterpret_cast<const float2*>(h + (size_t)d * 128 + lane * 2);
    float2 acc;
    acc.x = den * hself.x;
    acc.y = den * hself.y;

    const int start = (d == 0) ? 0 : rowptr[d - 1];
    const int end   = rowptr[d];

    #pragma unroll 4
    for (int j = start; j < end; ++j) {
        const int s = perm_src[j];                       // uniform -> broadcast
        const float asv = a_src[s * 2 + hd];             // broadcast per half-wave
        const float2 hv = *reinterpret_cast<const float2*>(h + (size_t)s * 128 + lane * 2);
        float lg = asv + adv;
        float l2 = lg > 0.f ? lg : NEG_SLOPE * lg;
        float ex = __expf(l2);
        den  += ex;
        acc.x = fmaf(ex, hv.x, acc.x);
        acc.y = fmaf(ex, hv.y, acc.y);
    }

    const float inv = 1.f / (den + 1e-16f);
    float2 o;
    o.x = acc.x * inv + bias[lane * 2];
    o.y = acc.y * inv + bias[lane * 2 + 1];
    *reinterpret_cast<float2*>(out + (size_t)d * 128 + lane * 2) = o;
}

extern "C" void kernel_launch(void* const* d_in, const int* in_sizes, int n_in,
                              void* d_out, int out_size, void* d_ws, size_t ws_size,
                              hipStream_t stream) {
    const int*   edge  = (const int*)  d_in[0];   // (2,E) int32
    const float* users = (const float*)d_in[1];   // (N_USERS,64) f32
    const float* items = (const float*)d_in[2];   // (N_ITEMS,64) f32
    const float* W     = (const float*)d_in[3];   // (64,128) f32
    const float* att_s = (const float*)d_in[4];   // (2,64) f32
    const float* att_d = (const float*)d_in[5];   // (2,64) f32
    const float* bias  = (const float*)d_in[6];   // (128,) f32

    const int E       = in_sizes[0] / 2;
    const int n_users = in_sizes[1] / 64;
    const int n_items = in_sizes[2] / 64;
    const int N       = n_users + n_items;

    float* out = (float*)d_out;

    // Workspace layout:
    // h (N*128 f32) | a_src (N*2) | a_dst (N*2) | cnt (N i32) | rowptr (N i32)
    // | perm_src (E i32)   -- total ~43.5 MB
    char* ws = (char*)d_ws;
    float* h        = (float*)ws;  ws += (size_t)N * 128 * sizeof(float);
    float* a_src    = (float*)ws;  ws += (size_t)N * 2   * sizeof(float);
    float* a_dst    = (float*)ws;  ws += (size_t)N * 2   * sizeof(float);
    int*   cnt      = (int*)ws;    ws += (size_t)N * sizeof(int);
    int*   rowptr   = (int*)ws;    ws += (size_t)N * sizeof(int);
    int*   perm_src = (int*)ws;

    const int* src = edge;
    const int* dst = edge + E;

    hipMemsetAsync(cnt, 0, (size_t)N * sizeof(int), stream);

    k_node<<<N, 128, 0, stream>>>(users, items, W, att_s, att_d,
                                  h, a_src, a_dst, n_users);

    k_hist<<<(E + 255) / 256, 256, 0, stream>>>(dst, cnt, E);

    k_scan<<<1, 1024, 0, stream>>>(cnt, rowptr, N);

    k_scatter<<<(E + 255) / 256, 256, 0, stream>>>(src, dst, rowptr, perm_src, E);

    k_gather<<<(N + 1) / 2, 128, 0, stream>>>(rowptr, perm_src, a_src, a_dst,
                                              h, bias, out, N);
}

// Round 3
// 482.211 us; speedup vs baseline: 3.9356x; 1.2482x over previous
//
#include <hip/hip_runtime.h>
#include <math.h>

#define NEG_SLOPE 0.2f
#define NPART 8          // one partition per XCD (blockIdx%8 ~ XCD round-robin)
#define CHUNK 2048       // edges per block pass (256 thr x 8)

// ---------------------------------------------------------------------------
// K1: per-node linear transform + attention logits.
// One block (128 threads = 2 waves) per node; wave w == head w.
// W is 32 KB == L1 size, so repeated reads hit L1/L2.
// ---------------------------------------------------------------------------
__global__ void k_node(const float* __restrict__ users,
                       const float* __restrict__ items,
                       const float* __restrict__ W,
                       const float* __restrict__ att_src,
                       const float* __restrict__ att_dst,
                       float* __restrict__ h,
                       float* __restrict__ a_src,
                       float* __restrict__ a_dst,
                       int n_users)
{
    const int node = blockIdx.x;
    const int tid  = threadIdx.x;           // 0..127 == output column
    __shared__ float xs[64];

    const float* xrow = (node < n_users)
        ? (users + (size_t)node * 64)
        : (items + (size_t)(node - n_users) * 64);
    if (tid < 64) xs[tid] = xrow[tid];
    __syncthreads();

    float sum = 0.f;
    #pragma unroll
    for (int k = 0; k < 64; ++k)
        sum = fmaf(xs[k], W[k * 128 + tid], sum);   // coalesced per k

    h[(size_t)node * 128 + tid] = sum;

    float vs = sum * att_src[tid];
    float vd = sum * att_dst[tid];
    #pragma unroll
    for (int off = 32; off > 0; off >>= 1) {
        vs += __shfl_down(vs, off);
        vd += __shfl_down(vd, off);
    }
    const int hd = tid >> 6;                // head == wave id
    if ((tid & 63) == 0) {
        a_src[node * 2 + hd] = vs;
        a_dst[node * 2 + hd] = vd;
    }
}

// ---------------------------------------------------------------------------
// K2: XCD-partitioned histogram. Each (chunk, part) block reads CHUNK edges
// and histograms only dsts in its partition -> atomics stay in one L2.
// ---------------------------------------------------------------------------
__global__ void k_hist(const int* __restrict__ dst, int* __restrict__ cnt,
                       int nedges, int part_size)
{
    const int part  = blockIdx.x & (NPART - 1);
    const int base  = (blockIdx.x >> 3) * CHUNK;
    const int lo    = part * part_size;
    const int hi    = lo + part_size;
    #pragma unroll
    for (int k = 0; k < CHUNK / 256; ++k) {
        int i = base + k * 256 + threadIdx.x;
        if (i < nedges) {
            int d = dst[i];
            if (d >= lo && d < hi) atomicAdd(&cnt[d], 1);
        }
    }
}

// ---------------------------------------------------------------------------
// K3a/b/c: 3-phase exclusive scan of cnt -> rowptr (multi-block, low latency)
// ---------------------------------------------------------------------------
__global__ void k_scan1(const int* __restrict__ cnt, int* __restrict__ rowptr,
                        int* __restrict__ blocksum, int n)
{
    __shared__ int sm[17];
    const int i    = blockIdx.x * 1024 + threadIdx.x;
    const int lane = threadIdx.x & 63;
    const int wid  = threadIdx.x >> 6;     // 0..15
    int v = (i < n) ? cnt[i] : 0;

    int incl = v;
    #pragma unroll
    for (int off = 1; off < 64; off <<= 1) {
        int t = __shfl_up(incl, off);
        if (lane >= off) incl += t;
    }
    if (lane == 63) sm[wid] = incl;
    __syncthreads();

    if (wid == 0 && lane < 16) {
        int ws = sm[lane];
        int wincl = ws;
        #pragma unroll
        for (int off = 1; off < 16; off <<= 1) {
            int t = __shfl_up(wincl, off);
            if (lane >= off) wincl += t;
        }
        sm[lane] = wincl - ws;              // exclusive wave offset
        if (lane == 15) sm[16] = wincl;     // block total
    }
    __syncthreads();

    if (i < n) rowptr[i] = sm[wid] + incl - v;   // block-local exclusive
    if (threadIdx.x == 0) blocksum[blockIdx.x] = sm[16];
}

__global__ void k_scan2(const int* __restrict__ blocksum,
                        int* __restrict__ blockoff, int nb)
{
    const int lane = threadIdx.x;          // 64 threads, 1 wave
    int running = 0;
    for (int base = 0; base < nb; base += 64) {
        int v = (base + lane < nb) ? blocksum[base + lane] : 0;
        int incl = v;
        #pragma unroll
        for (int off = 1; off < 64; off <<= 1) {
            int t = __shfl_up(incl, off);
            if (lane >= off) incl += t;
        }
        if (base + lane < nb) blockoff[base + lane] = running + incl - v;
        running += __shfl(incl, 63);
    }
}

__global__ void k_scan3(int* __restrict__ rowptr,
                        const int* __restrict__ blockoff, int n)
{
    int i = blockIdx.x * 256 + threadIdx.x;
    if (i < n) rowptr[i] += blockoff[i >> 10];
}

// ---------------------------------------------------------------------------
// K4: XCD-partitioned scatter. Block (chunk, part) reads CHUNK edges, places
// only those with dst in its partition. perm_src region for partition p is
// contiguous and written only from (presumed) XCD p -> no cross-XCD dirty
// line ping-pong. After this kernel rowptr[d] == exclusive END of segment d.
// ---------------------------------------------------------------------------
__global__ void k_scatter(const int* __restrict__ src, const int* __restrict__ dst,
                          int* __restrict__ rowptr, int* __restrict__ perm_src,
                          int nedges, int part_size)
{
    const int part  = blockIdx.x & (NPART - 1);
    const int base  = (blockIdx.x >> 3) * CHUNK;
    const int lo    = part * part_size;
    const int hi    = lo + part_size;
    #pragma unroll
    for (int k = 0; k < CHUNK / 256; ++k) {
        int i = base + k * 256 + threadIdx.x;
        if (i < nedges) {
            int d = dst[i];
            int s = src[i];                 // unconditional, coalesced
            if (d >= lo && d < hi) {
                int pos = atomicAdd(&rowptr[d], 1);
                perm_src[pos] = s;
            }
        }
    }
}

// ---------------------------------------------------------------------------
// K5: gather-accumulate. One wave per destination node; lane owns a float2
// of the 128 channels (lanes 0-31 head0, 32-63 head1). No atomics.
// ---------------------------------------------------------------------------
__global__ void k_gather(const int* __restrict__ rowptr,
                         const int* __restrict__ perm_src,
                         const float* __restrict__ a_src,
                         const float* __restrict__ a_dst,
                         const float* __restrict__ h,
                         const float* __restrict__ bias,
                         float* __restrict__ out,
                         int nnodes)
{
    const int d = blockIdx.x * 2 + (threadIdx.x >> 6);  // 2 nodes per block
    if (d >= nnodes) return;
    const int lane = threadIdx.x & 63;
    const int hd   = lane >> 5;            // lanes 0-31: head0, 32-63: head1

    const float adv = a_dst[d * 2 + hd];

    // self loop
    float logit = a_src[d * 2 + hd] + adv;
    float lr    = logit > 0.f ? logit : NEG_SLOPE * logit;
    float den   = __expf(lr);
    const float2 hself = *reinterpret_cast<const float2*>(h + (size_t)d * 128 + lane * 2);
    float2 acc;
    acc.x = den * hself.x;
    acc.y = den * hself.y;

    const int start = (d == 0) ? 0 : rowptr[d - 1];
    const int end   = rowptr[d];

    #pragma unroll 4
    for (int j = start; j < end; ++j) {
        const int s = perm_src[j];                       // wave-uniform
        const float asv = a_src[s * 2 + hd];
        const float2 hv = *reinterpret_cast<const float2*>(h + (size_t)s * 128 + lane * 2);
        float lg = asv + adv;
        float l2 = lg > 0.f ? lg : NEG_SLOPE * lg;
        float ex = __expf(l2);
        den  += ex;
        acc.x = fmaf(ex, hv.x, acc.x);
        acc.y = fmaf(ex, hv.y, acc.y);
    }

    const float inv = 1.f / (den + 1e-16f);
    float2 o;
    o.x = acc.x * inv + bias[lane * 2];
    o.y = acc.y * inv + bias[lane * 2 + 1];
    *reinterpret_cast<float2*>(out + (size_t)d * 128 + lane * 2) = o;
}

extern "C" void kernel_launch(void* const* d_in, const int* in_sizes, int n_in,
                              void* d_out, int out_size, void* d_ws, size_t ws_size,
                              hipStream_t stream) {
    const int*   edge  = (const int*)  d_in[0];   // (2,E) int32
    const float* users = (const float*)d_in[1];   // (N_USERS,64) f32
    const float* items = (const float*)d_in[2];   // (N_ITEMS,64) f32
    const float* W     = (const float*)d_in[3];   // (64,128) f32
    const float* att_s = (const float*)d_in[4];   // (2,64) f32
    const float* att_d = (const float*)d_in[5];   // (2,64) f32
    const float* bias  = (const float*)d_in[6];   // (128,) f32

    const int E       = in_sizes[0] / 2;
    const int n_users = in_sizes[1] / 64;
    const int n_items = in_sizes[2] / 64;
    const int N       = n_users + n_items;

    float* out = (float*)d_out;

    // Workspace layout:
    // h (N*128 f32) | a_src (N*2) | a_dst (N*2) | cnt (N i32) | rowptr (N i32)
    // | perm_src (E i32) | blocksum | blockoff
    char* ws = (char*)d_ws;
    float* h        = (float*)ws;  ws += (size_t)N * 128 * sizeof(float);
    float* a_src    = (float*)ws;  ws += (size_t)N * 2   * sizeof(float);
    float* a_dst    = (float*)ws;  ws += (size_t)N * 2   * sizeof(float);
    int*   cnt      = (int*)ws;    ws += (size_t)N * sizeof(int);
    int*   rowptr   = (int*)ws;    ws += (size_t)N * sizeof(int);
    int*   perm_src = (int*)ws;    ws += (size_t)E * sizeof(int);
    int*   blocksum = (int*)ws;    ws += 1024 * sizeof(int);
    int*   blockoff = (int*)ws;

    const int* src = edge;
    const int* dst = edge + E;

    const int part_size  = (N + NPART - 1) / NPART;
    const int nchunks    = (E + CHUNK - 1) / CHUNK;
    const int part_grid  = nchunks * NPART;
    const int scan_blocks = (N + 1023) / 1024;

    hipMemsetAsync(cnt, 0, (size_t)N * sizeof(int), stream);

    k_node<<<N, 128, 0, stream>>>(users, items, W, att_s, att_d,
                                  h, a_src, a_dst, n_users);

    k_hist<<<part_grid, 256, 0, stream>>>(dst, cnt, E, part_size);

    k_scan1<<<scan_blocks, 1024, 0, stream>>>(cnt, rowptr, blocksum, N);
    k_scan2<<<1, 64, 0, stream>>>(blocksum, blockoff, scan_blocks);
    k_scan3<<<(N + 255) / 256, 256, 0, stream>>>(rowptr, blockoff, N);

    k_scatter<<<part_grid, 256, 0, stream>>>(src, dst, rowptr, perm_src,
                                             E, part_size);

    k_gather<<<(N + 1) / 2, 128, 0, stream>>>(rowptr, perm_src, a_src, a_dst,
                                              h, bias, out, N);
}

// Round 4
// 436.845 us; speedup vs baseline: 4.3443x; 1.1039x over previous
//
#include <hip/hip_runtime.h>
#include <math.h>

#define NEG_SLOPE 0.2f
#define NPART 8          // one partition per XCD (blockIdx%8 ~ XCD round-robin)
#define CHUNK 2048       // edges per block pass (256 thr x 8)

__device__ __forceinline__ unsigned short f2bf(float f) {
    unsigned u = __float_as_uint(f);
    u = (u + 0x7FFFu + ((u >> 16) & 1u)) >> 16;    // round-nearest-even
    return (unsigned short)u;
}
__device__ __forceinline__ float bf2f(unsigned short b) {
    return __uint_as_float(((unsigned)b) << 16);
}

// ---------------------------------------------------------------------------
// K1: per-node linear transform + attention logits. h stored in bf16
// (halves gather traffic; f32 accumulate downstream keeps error ~1e-3).
// One block (128 threads = 2 waves) per node; wave w == head w.
// ---------------------------------------------------------------------------
__global__ void k_node(const float* __restrict__ users,
                       const float* __restrict__ items,
                       const float* __restrict__ W,
                       const float* __restrict__ att_src,
                       const float* __restrict__ att_dst,
                       unsigned short* __restrict__ hb,
                       float* __restrict__ a_src,
                       float* __restrict__ a_dst,
                       int n_users)
{
    const int node = blockIdx.x;
    const int tid  = threadIdx.x;           // 0..127 == output column
    __shared__ float xs[64];

    const float* xrow = (node < n_users)
        ? (users + (size_t)node * 64)
        : (items + (size_t)(node - n_users) * 64);
    if (tid < 64) xs[tid] = xrow[tid];
    __syncthreads();

    float sum = 0.f;
    #pragma unroll
    for (int k = 0; k < 64; ++k)
        sum = fmaf(xs[k], W[k * 128 + tid], sum);   // coalesced per k

    hb[(size_t)node * 128 + tid] = f2bf(sum);

    float vs = sum * att_src[tid];
    float vd = sum * att_dst[tid];
    #pragma unroll
    for (int off = 32; off > 0; off >>= 1) {
        vs += __shfl_down(vs, off);
        vd += __shfl_down(vd, off);
    }
    const int hd = tid >> 6;                // head == wave id
    if ((tid & 63) == 0) {
        a_src[node * 2 + hd] = vs;
        a_dst[node * 2 + hd] = vd;
    }
}

// ---------------------------------------------------------------------------
// K2: XCD-partitioned histogram (atomics stay in one L2).
// ---------------------------------------------------------------------------
__global__ void k_hist(const int* __restrict__ dst, int* __restrict__ cnt,
                       int nedges, int part_size)
{
    const int part  = blockIdx.x & (NPART - 1);
    const int base  = (blockIdx.x >> 3) * CHUNK;
    const int lo    = part * part_size;
    const int hi    = lo + part_size;
    #pragma unroll
    for (int k = 0; k < CHUNK / 256; ++k) {
        int i = base + k * 256 + threadIdx.x;
        if (i < nedges) {
            int d = dst[i];
            if (d >= lo && d < hi) atomicAdd(&cnt[d], 1);
        }
    }
}

// ---------------------------------------------------------------------------
// K3a/b/c: 3-phase exclusive scan of cnt -> rowptr
// ---------------------------------------------------------------------------
__global__ void k_scan1(const int* __restrict__ cnt, int* __restrict__ rowptr,
                        int* __restrict__ blocksum, int n)
{
    __shared__ int sm[17];
    const int i    = blockIdx.x * 1024 + threadIdx.x;
    const int lane = threadIdx.x & 63;
    const int wid  = threadIdx.x >> 6;     // 0..15
    int v = (i < n) ? cnt[i] : 0;

    int incl = v;
    #pragma unroll
    for (int off = 1; off < 64; off <<= 1) {
        int t = __shfl_up(incl, off);
        if (lane >= off) incl += t;
    }
    if (lane == 63) sm[wid] = incl;
    __syncthreads();

    if (wid == 0 && lane < 16) {
        int ws = sm[lane];
        int wincl = ws;
        #pragma unroll
        for (int off = 1; off < 16; off <<= 1) {
            int t = __shfl_up(wincl, off);
            if (lane >= off) wincl += t;
        }
        sm[lane] = wincl - ws;              // exclusive wave offset
        if (lane == 15) sm[16] = wincl;     // block total
    }
    __syncthreads();

    if (i < n) rowptr[i] = sm[wid] + incl - v;   // block-local exclusive
    if (threadIdx.x == 0) blocksum[blockIdx.x] = sm[16];
}

__global__ void k_scan2(const int* __restrict__ blocksum,
                        int* __restrict__ blockoff, int nb)
{
    const int lane = threadIdx.x;          // 64 threads, 1 wave
    int running = 0;
    for (int base = 0; base < nb; base += 64) {
        int v = (base + lane < nb) ? blocksum[base + lane] : 0;
        int incl = v;
        #pragma unroll
        for (int off = 1; off < 64; off <<= 1) {
            int t = __shfl_up(incl, off);
            if (lane >= off) incl += t;
        }
        if (base + lane < nb) blockoff[base + lane] = running + incl - v;
        running += __shfl(incl, 63);
    }
}

__global__ void k_scan3(int* __restrict__ rowptr,
                        const int* __restrict__ blockoff, int n)
{
    int i = blockIdx.x * 256 + threadIdx.x;
    if (i < n) rowptr[i] += blockoff[i >> 10];
}

// ---------------------------------------------------------------------------
// K4: XCD-partitioned scatter. After this, rowptr[d] == exclusive END of
// segment d.
// ---------------------------------------------------------------------------
__global__ void k_scatter(const int* __restrict__ src, const int* __restrict__ dst,
                          int* __restrict__ rowptr, int* __restrict__ perm_src,
                          int nedges, int part_size)
{
    const int part  = blockIdx.x & (NPART - 1);
    const int base  = (blockIdx.x >> 3) * CHUNK;
    const int lo    = part * part_size;
    const int hi    = lo + part_size;
    #pragma unroll
    for (int k = 0; k < CHUNK / 256; ++k) {
        int i = base + k * 256 + threadIdx.x;
        if (i < nedges) {
            int d = dst[i];
            int s = src[i];                 // unconditional, coalesced
            if (d >= lo && d < hi) {
                int pos = atomicAdd(&rowptr[d], 1);
                perm_src[pos] = s;
            }
        }
    }
}

// ---------------------------------------------------------------------------
// K5: gather-accumulate, 2 edges per wave (half-wave per edge).
// Lane = half*32 + sl; sl owns channels sl*4..sl*4+3 (bf16x4 = 8B load,
// 256 B coalesced row per half-wave). f32 accumulate; cross-half merge by
// shfl_xor(32). Self-loop = virtual edge 0. No atomics.
// ---------------------------------------------------------------------------
__global__ void k_gather(const int* __restrict__ rowptr,
                         const int* __restrict__ perm_src,
                         const float* __restrict__ a_src,
                         const float* __restrict__ a_dst,
                         const unsigned short* __restrict__ hb,
                         const float* __restrict__ bias,
                         float* __restrict__ out,
                         int nnodes)
{
    const int d = blockIdx.x * 2 + (threadIdx.x >> 6);  // 2 nodes per block
    if (d >= nnodes) return;
    const int lane = threadIdx.x & 63;
    const int half = lane >> 5;            // which edge of the running pair
    const int sl   = lane & 31;            // channel group: 4 ch each
    const int hd   = sl >> 4;              // head of those channels

    const float adv = a_dst[d * 2 + hd];
    const int start = (d == 0) ? 0 : rowptr[d - 1];
    const int cnt1  = rowptr[d] - start + 1;     // +1 for self loop

    float ax = 0.f, ay = 0.f, az = 0.f, aw = 0.f;
    float den = 0.f;

    #pragma unroll 2
    for (int v = half; v < cnt1; v += 2) {
        int s = d;
        if (v > 0) s = perm_src[start + v - 1];  // uniform per half-wave
        float asv = a_src[s * 2 + hd];
        ushort4 hv = *reinterpret_cast<const ushort4*>(hb + (size_t)s * 128 + sl * 4);
        float lg = asv + adv;
        float l2 = lg > 0.f ? lg : NEG_SLOPE * lg;
        float ex = __expf(l2);
        den += ex;
        ax = fmaf(ex, bf2f(hv.x), ax);
        ay = fmaf(ex, bf2f(hv.y), ay);
        az = fmaf(ex, bf2f(hv.z), az);
        aw = fmaf(ex, bf2f(hv.w), aw);
    }

    // merge the two half-wave accumulators
    ax += __shfl_xor(ax, 32);
    ay += __shfl_xor(ay, 32);
    az += __shfl_xor(az, 32);
    aw += __shfl_xor(aw, 32);
    den += __shfl_xor(den, 32);

    if (half == 0) {
        const float inv = 1.f / (den + 1e-16f);
        float4 o;
        o.x = ax * inv + bias[sl * 4];
        o.y = ay * inv + bias[sl * 4 + 1];
        o.z = az * inv + bias[sl * 4 + 2];
        o.w = aw * inv + bias[sl * 4 + 3];
        *reinterpret_cast<float4*>(out + (size_t)d * 128 + sl * 4) = o;
    }
}

extern "C" void kernel_launch(void* const* d_in, const int* in_sizes, int n_in,
                              void* d_out, int out_size, void* d_ws, size_t ws_size,
                              hipStream_t stream) {
    const int*   edge  = (const int*)  d_in[0];   // (2,E) int32
    const float* users = (const float*)d_in[1];   // (N_USERS,64) f32
    const float* items = (const float*)d_in[2];   // (N_ITEMS,64) f32
    const float* W     = (const float*)d_in[3];   // (64,128) f32
    const float* att_s = (const float*)d_in[4];   // (2,64) f32
    const float* att_d = (const float*)d_in[5];   // (2,64) f32
    const float* bias  = (const float*)d_in[6];   // (128,) f32

    const int E       = in_sizes[0] / 2;
    const int n_users = in_sizes[1] / 64;
    const int n_items = in_sizes[2] / 64;
    const int N       = n_users + n_items;

    float* out = (float*)d_out;

    // Workspace layout:
    // hb (N*128 bf16) | a_src (N*2 f32) | a_dst (N*2 f32) | cnt (N i32)
    // | rowptr (N i32) | perm_src (E i32) | blocksum | blockoff
    char* ws = (char*)d_ws;
    unsigned short* hb = (unsigned short*)ws;
    ws += (size_t)N * 128 * sizeof(unsigned short);
    float* a_src    = (float*)ws;  ws += (size_t)N * 2 * sizeof(float);
    float* a_dst    = (float*)ws;  ws += (size_t)N * 2 * sizeof(float);
    int*   cnt      = (int*)ws;    ws += (size_t)N * sizeof(int);
    int*   rowptr   = (int*)ws;    ws += (size_t)N * sizeof(int);
    int*   perm_src = (int*)ws;    ws += (size_t)E * sizeof(int);
    int*   blocksum = (int*)ws;    ws += 1024 * sizeof(int);
    int*   blockoff = (int*)ws;

    const int* src = edge;
    const int* dst = edge + E;

    const int part_size   = (N + NPART - 1) / NPART;
    const int nchunks     = (E + CHUNK - 1) / CHUNK;
    const int part_grid   = nchunks * NPART;
    const int scan_blocks = (N + 1023) / 1024;

    hipMemsetAsync(cnt, 0, (size_t)N * sizeof(int), stream);

    k_node<<<N, 128, 0, stream>>>(users, items, W, att_s, att_d,
                                  hb, a_src, a_dst, n_users);

    k_hist<<<part_grid, 256, 0, stream>>>(dst, cnt, E, part_size);

    k_scan1<<<scan_blocks, 1024, 0, stream>>>(cnt, rowptr, blocksum, N);
    k_scan2<<<1, 64, 0, stream>>>(blocksum, blockoff, scan_blocks);
    k_scan3<<<(N + 255) / 256, 256, 0, stream>>>(rowptr, blockoff, N);

    k_scatter<<<part_grid, 256, 0, stream>>>(src, dst, rowptr, perm_src,
                                             E, part_size);

    k_gather<<<(N + 1) / 2, 128, 0, stream>>>(rowptr, perm_src, a_src, a_dst,
                                              hb, bias, out, N);
}

// Round 5
// 421.210 us; speedup vs baseline: 4.5055x; 1.0371x over previous
//
#include <hip/hip_runtime.h>
#include <math.h>

#define NEG_SLOPE 0.2f
#define NPART 8          // one partition per XCD (blockIdx%8 ~ XCD round-robin)
#define CHUNK 2048       // edges per block pass (256 thr x 8)

typedef unsigned short ushort8_v __attribute__((ext_vector_type(8)));

__device__ __forceinline__ unsigned short f2bf(float f) {
    unsigned u = __float_as_uint(f);
    u = (u + 0x7FFFu + ((u >> 16) & 1u)) >> 16;    // round-nearest-even
    return (unsigned short)u;
}
__device__ __forceinline__ float bf2f(unsigned short b) {
    return __uint_as_float(((unsigned)b) << 16);
}
__device__ __forceinline__ float lrelu(float x) {
    return x > 0.f ? x : NEG_SLOPE * x;
}

// ---------------------------------------------------------------------------
// K1: per-node linear transform + attention logits; h stored bf16.
// Also zeroes cnt[node] (replaces the memset dispatch).
// One block (128 threads = 2 waves) per node; wave w == head w.
// ---------------------------------------------------------------------------
__global__ void k_node(const float* __restrict__ users,
                       const float* __restrict__ items,
                       const float* __restrict__ W,
                       const float* __restrict__ att_src,
                       const float* __restrict__ att_dst,
                       unsigned short* __restrict__ hb,
                       float* __restrict__ a_src,
                       float* __restrict__ a_dst,
                       int* __restrict__ cnt,
                       int n_users)
{
    const int node = blockIdx.x;
    const int tid  = threadIdx.x;           // 0..127 == output column
    __shared__ float xs[64];

    if (tid == 0) cnt[node] = 0;

    const float* xrow = (node < n_users)
        ? (users + (size_t)node * 64)
        : (items + (size_t)(node - n_users) * 64);
    if (tid < 64) xs[tid] = xrow[tid];
    __syncthreads();

    float sum = 0.f;
    #pragma unroll
    for (int k = 0; k < 64; ++k)
        sum = fmaf(xs[k], W[k * 128 + tid], sum);   // coalesced per k

    hb[(size_t)node * 128 + tid] = f2bf(sum);

    float vs = sum * att_src[tid];
    float vd = sum * att_dst[tid];
    #pragma unroll
    for (int off = 32; off > 0; off >>= 1) {
        vs += __shfl_down(vs, off);
        vd += __shfl_down(vd, off);
    }
    const int hd = tid >> 6;                // head == wave id
    if ((tid & 63) == 0) {
        a_src[node * 2 + hd] = vs;
        a_dst[node * 2 + hd] = vd;
    }
}

// ---------------------------------------------------------------------------
// K2: XCD-partitioned histogram (atomics stay in one L2).
// ---------------------------------------------------------------------------
__global__ void k_hist(const int* __restrict__ dst, int* __restrict__ cnt,
                       int nedges, int part_size)
{
    const int part  = blockIdx.x & (NPART - 1);
    const int base  = (blockIdx.x >> 3) * CHUNK;
    const int lo    = part * part_size;
    const int hi    = lo + part_size;
    #pragma unroll
    for (int k = 0; k < CHUNK / 256; ++k) {
        int i = base + k * 256 + threadIdx.x;
        if (i < nedges) {
            int d = dst[i];
            if (d >= lo && d < hi) atomicAdd(&cnt[d], 1);
        }
    }
}

// ---------------------------------------------------------------------------
// K3a/b/c: 3-phase exclusive scan of cnt -> rowptr
// ---------------------------------------------------------------------------
__global__ void k_scan1(const int* __restrict__ cnt, int* __restrict__ rowptr,
                        int* __restrict__ blocksum, int n)
{
    __shared__ int sm[17];
    const int i    = blockIdx.x * 1024 + threadIdx.x;
    const int lane = threadIdx.x & 63;
    const int wid  = threadIdx.x >> 6;     // 0..15
    int v = (i < n) ? cnt[i] : 0;

    int incl = v;
    #pragma unroll
    for (int off = 1; off < 64; off <<= 1) {
        int t = __shfl_up(incl, off);
        if (lane >= off) incl += t;
    }
    if (lane == 63) sm[wid] = incl;
    __syncthreads();

    if (wid == 0 && lane < 16) {
        int ws = sm[lane];
        int wincl = ws;
        #pragma unroll
        for (int off = 1; off < 16; off <<= 1) {
            int t = __shfl_up(wincl, off);
            if (lane >= off) wincl += t;
        }
        sm[lane] = wincl - ws;              // exclusive wave offset
        if (lane == 15) sm[16] = wincl;     // block total
    }
    __syncthreads();

    if (i < n) rowptr[i] = sm[wid] + incl - v;   // block-local exclusive
    if (threadIdx.x == 0) blocksum[blockIdx.x] = sm[16];
}

__global__ void k_scan2(const int* __restrict__ blocksum,
                        int* __restrict__ blockoff, int nb)
{
    const int lane = threadIdx.x;          // 64 threads, 1 wave
    int running = 0;
    for (int base = 0; base < nb; base += 64) {
        int v = (base + lane < nb) ? blocksum[base + lane] : 0;
        int incl = v;
        #pragma unroll
        for (int off = 1; off < 64; off <<= 1) {
            int t = __shfl_up(incl, off);
            if (lane >= off) incl += t;
        }
        if (base + lane < nb) blockoff[base + lane] = running + incl - v;
        running += __shfl(incl, 63);
    }
}

__global__ void k_scan3(int* __restrict__ rowptr,
                        const int* __restrict__ blockoff, int n)
{
    int i = blockIdx.x * 256 + threadIdx.x;
    if (i < n) rowptr[i] += blockoff[i >> 10];
}

// ---------------------------------------------------------------------------
// K4: XCD-partitioned scatter + per-edge attention weight precompute.
//   pos = bump(rowptr[d]); perm[pos]=s; pex[pos]=exp(lrelu(a_src[s]+a_dst[d]))
// (both heads). Moves the exp + random a_src reads out of the gather loop,
// overlapped here with atomic latency. After this kernel rowptr[d] ==
// exclusive END of segment d.
// ---------------------------------------------------------------------------
__global__ void k_scatter(const int* __restrict__ src, const int* __restrict__ dst,
                          const float* __restrict__ a_src,
                          const float* __restrict__ a_dst,
                          int* __restrict__ rowptr, int* __restrict__ perm_src,
                          float2* __restrict__ pex,
                          int nedges, int part_size)
{
    const int part  = blockIdx.x & (NPART - 1);
    const int base  = (blockIdx.x >> 3) * CHUNK;
    const int lo    = part * part_size;
    const int hi    = lo + part_size;
    #pragma unroll
    for (int k = 0; k < CHUNK / 256; ++k) {
        int i = base + k * 256 + threadIdx.x;
        if (i < nedges) {
            int d = dst[i];
            int s = src[i];                 // unconditional, coalesced
            if (d >= lo && d < hi) {
                int pos = atomicAdd(&rowptr[d], 1);
                const float2 as2 = *reinterpret_cast<const float2*>(a_src + 2 * s);
                const float2 ad2 = *reinterpret_cast<const float2*>(a_dst + 2 * d);
                float2 e;
                e.x = __expf(lrelu(as2.x + ad2.x));
                e.y = __expf(lrelu(as2.y + ad2.y));
                perm_src[pos] = s;
                pex[pos] = e;
            }
        }
    }
}

// ---------------------------------------------------------------------------
// K5: gather-accumulate. One wave per node; quarter-wave (16 lanes) per edge,
// 4 edges in flight. Lane sl owns channels sl*8..sl*8+7 (ushort8 = 16 B,
// 256 B coalesced row per quarter). Inner loop: 2 broadcast loads + 1 row
// load + 8 FMA — no exp, no random scalar gathers. Self-loop = virtual
// edge 0. Merge across quarters via shfl_xor(16/32). No atomics.
// ---------------------------------------------------------------------------
__global__ void k_gather(const int* __restrict__ rowptr,
                         const int* __restrict__ perm_src,
                         const float2* __restrict__ pex,
                         const float* __restrict__ a_src,
                         const float* __restrict__ a_dst,
                         const unsigned short* __restrict__ hb,
                         const float* __restrict__ bias,
                         float* __restrict__ out,
                         int nnodes)
{
    const int d = blockIdx.x * 4 + (threadIdx.x >> 6);  // wave per node
    if (d >= nnodes) return;
    const int lane = threadIdx.x & 63;
    const int q    = lane >> 4;            // quarter: which edge of the 4
    const int sl   = lane & 15;            // channel group: 8 ch each
    const int hd   = sl >> 3;              // head of those channels

    const float2 as2 = *reinterpret_cast<const float2*>(a_src + 2 * d);
    const float2 ad2 = *reinterpret_cast<const float2*>(a_dst + 2 * d);
    const float exs0 = __expf(lrelu(as2.x + ad2.x));
    const float exs1 = __expf(lrelu(as2.y + ad2.y));

    const int start = (d == 0) ? 0 : rowptr[d - 1];
    const int cnt1  = rowptr[d] - start + 1;     // +1 for self loop

    float acc[8];
    #pragma unroll
    for (int i = 0; i < 8; ++i) acc[i] = 0.f;
    float den = 0.f;

    #pragma unroll 2
    for (int v = q; v < cnt1; v += 4) {
        int s; float ex;
        if (v == 0) {
            s = d;  ex = hd ? exs1 : exs0;
        } else {
            const int j = start + v - 1;
            s = perm_src[j];
            const float2 e2 = pex[j];
            ex = hd ? e2.y : e2.x;
        }
        const ushort8_v hv = *reinterpret_cast<const ushort8_v*>(
            hb + (size_t)s * 128 + sl * 8);
        den += ex;
        #pragma unroll
        for (int i = 0; i < 8; ++i)
            acc[i] = fmaf(ex, bf2f(hv[i]), acc[i]);
    }

    // merge the four quarter accumulators
    #pragma unroll
    for (int off = 16; off <= 32; off <<= 1) {
        #pragma unroll
        for (int i = 0; i < 8; ++i) acc[i] += __shfl_xor(acc[i], off);
        den += __shfl_xor(den, off);
    }

    if (q == 0) {
        const float inv = 1.f / (den + 1e-16f);
        float4 o0, o1;
        o0.x = acc[0] * inv + bias[sl * 8 + 0];
        o0.y = acc[1] * inv + bias[sl * 8 + 1];
        o0.z = acc[2] * inv + bias[sl * 8 + 2];
        o0.w = acc[3] * inv + bias[sl * 8 + 3];
        o1.x = acc[4] * inv + bias[sl * 8 + 4];
        o1.y = acc[5] * inv + bias[sl * 8 + 5];
        o1.z = acc[6] * inv + bias[sl * 8 + 6];
        o1.w = acc[7] * inv + bias[sl * 8 + 7];
        float* op = out + (size_t)d * 128 + sl * 8;
        *reinterpret_cast<float4*>(op)     = o0;
        *reinterpret_cast<float4*>(op + 4) = o1;
    }
}

extern "C" void kernel_launch(void* const* d_in, const int* in_sizes, int n_in,
                              void* d_out, int out_size, void* d_ws, size_t ws_size,
                              hipStream_t stream) {
    const int*   edge  = (const int*)  d_in[0];   // (2,E) int32
    const float* users = (const float*)d_in[1];   // (N_USERS,64) f32
    const float* items = (const float*)d_in[2];   // (N_ITEMS,64) f32
    const float* W     = (const float*)d_in[3];   // (64,128) f32
    const float* att_s = (const float*)d_in[4];   // (2,64) f32
    const float* att_d = (const float*)d_in[5];   // (2,64) f32
    const float* bias  = (const float*)d_in[6];   // (128,) f32

    const int E       = in_sizes[0] / 2;
    const int n_users = in_sizes[1] / 64;
    const int n_items = in_sizes[2] / 64;
    const int N       = n_users + n_items;

    float* out = (float*)d_out;

    // Workspace layout (8-B alignment maintained):
    // hb (N*128 bf16) | pex (E float2) | a_src (N*2 f32) | a_dst (N*2 f32)
    // | cnt (N i32) | rowptr (N i32) | perm_src (E i32) | blocksum | blockoff
    char* ws = (char*)d_ws;
    unsigned short* hb = (unsigned short*)ws;
    ws += (size_t)N * 128 * sizeof(unsigned short);
    float2* pex     = (float2*)ws; ws += (size_t)E * sizeof(float2);
    float* a_src    = (float*)ws;  ws += (size_t)N * 2 * sizeof(float);
    float* a_dst    = (float*)ws;  ws += (size_t)N * 2 * sizeof(float);
    int*   cnt      = (int*)ws;    ws += (size_t)N * sizeof(int);
    int*   rowptr   = (int*)ws;    ws += (size_t)N * sizeof(int);
    int*   perm_src = (int*)ws;    ws += (size_t)E * sizeof(int);
    int*   blocksum = (int*)ws;    ws += 1024 * sizeof(int);
    int*   blockoff = (int*)ws;

    const int* src = edge;
    const int* dst = edge + E;

    const int part_size   = (N + NPART - 1) / NPART;
    const int nchunks     = (E + CHUNK - 1) / CHUNK;
    const int part_grid   = nchunks * NPART;
    const int scan_blocks = (N + 1023) / 1024;

    k_node<<<N, 128, 0, stream>>>(users, items, W, att_s, att_d,
                                  hb, a_src, a_dst, cnt, n_users);

    k_hist<<<part_grid, 256, 0, stream>>>(dst, cnt, E, part_size);

    k_scan1<<<scan_blocks, 1024, 0, stream>>>(cnt, rowptr, blocksum, N);
    k_scan2<<<1, 64, 0, stream>>>(blocksum, blockoff, scan_blocks);
    k_scan3<<<(N + 255) / 256, 256, 0, stream>>>(rowptr, blockoff, N);

    k_scatter<<<part_grid, 256, 0, stream>>>(src, dst, a_src, a_dst,
                                             rowptr, perm_src, pex,
                                             E, part_size);

    k_gather<<<(N + 3) / 4, 256, 0, stream>>>(rowptr, perm_src, pex,
                                              a_src, a_dst, hb, bias, out, N);
}

// Round 6
// 409.678 us; speedup vs baseline: 4.6324x; 1.0281x over previous
//
#include <hip/hip_runtime.h>
#include <hip/hip_fp16.h>
#include <math.h>

#define NEG_SLOPE 0.2f
#define NPART 8          // one partition per XCD (blockIdx%8 ~ XCD round-robin)
#define CHUNK 2048       // edges per block pass (256 thr x 8)

typedef unsigned short ushort8_v __attribute__((ext_vector_type(8)));

__device__ __forceinline__ unsigned short f2bf(float f) {
    unsigned u = __float_as_uint(f);
    u = (u + 0x7FFFu + ((u >> 16) & 1u)) >> 16;    // round-nearest-even
    return (unsigned short)u;
}
__device__ __forceinline__ float bf2f(unsigned short b) {
    return __uint_as_float(((unsigned)b) << 16);
}
__device__ __forceinline__ float lrelu(float x) {
    return x > 0.f ? x : NEG_SLOPE * x;
}
__device__ __forceinline__ unsigned short f2h_bits(float f) {
    __half_raw hr = __half_raw(__float2half_rn(f));
    return hr.x;
}
__device__ __forceinline__ float h2f_bits(unsigned short u) {
    __half_raw hr; hr.x = u;
    return __half2float(__half(hr));
}

// ---------------------------------------------------------------------------
// K1: per-node linear transform + attention logits; h stored bf16.
// Also zeroes cnt[node] (replaces the memset dispatch).
// One block (128 threads = 2 waves) per node; wave w == head w.
// ---------------------------------------------------------------------------
__global__ void k_node(const float* __restrict__ users,
                       const float* __restrict__ items,
                       const float* __restrict__ W,
                       const float* __restrict__ att_src,
                       const float* __restrict__ att_dst,
                       unsigned short* __restrict__ hb,
                       float* __restrict__ a_src,
                       float* __restrict__ a_dst,
                       int* __restrict__ cnt,
                       int n_users)
{
    const int node = blockIdx.x;
    const int tid  = threadIdx.x;           // 0..127 == output column
    __shared__ float xs[64];

    if (tid == 0) cnt[node] = 0;

    const float* xrow = (node < n_users)
        ? (users + (size_t)node * 64)
        : (items + (size_t)(node - n_users) * 64);
    if (tid < 64) xs[tid] = xrow[tid];
    __syncthreads();

    float sum = 0.f;
    #pragma unroll
    for (int k = 0; k < 64; ++k)
        sum = fmaf(xs[k], W[k * 128 + tid], sum);   // coalesced per k

    hb[(size_t)node * 128 + tid] = f2bf(sum);

    float vs = sum * att_src[tid];
    float vd = sum * att_dst[tid];
    #pragma unroll
    for (int off = 32; off > 0; off >>= 1) {
        vs += __shfl_down(vs, off);
        vd += __shfl_down(vd, off);
    }
    const int hd = tid >> 6;                // head == wave id
    if ((tid & 63) == 0) {
        a_src[node * 2 + hd] = vs;
        a_dst[node * 2 + hd] = vd;
    }
}

// ---------------------------------------------------------------------------
// K2: XCD-partitioned histogram (atomics stay in one L2).
// ---------------------------------------------------------------------------
__global__ void k_hist(const int* __restrict__ dst, int* __restrict__ cnt,
                       int nedges, int part_size)
{
    const int part  = blockIdx.x & (NPART - 1);
    const int base  = (blockIdx.x >> 3) * CHUNK;
    const int lo    = part * part_size;
    const int hi    = lo + part_size;
    #pragma unroll
    for (int k = 0; k < CHUNK / 256; ++k) {
        int i = base + k * 256 + threadIdx.x;
        if (i < nedges) {
            int d = dst[i];
            if (d >= lo && d < hi) atomicAdd(&cnt[d], 1);
        }
    }
}

// ---------------------------------------------------------------------------
// K3a/b: scan. rowptr stays BLOCK-LOCAL exclusive; blockoff carries the
// cross-block offsets (folded into scatter/gather index math — no scan3).
// ---------------------------------------------------------------------------
__global__ void k_scan1(const int* __restrict__ cnt, int* __restrict__ rowptr,
                        int* __restrict__ blocksum, int n)
{
    __shared__ int sm[17];
    const int i    = blockIdx.x * 1024 + threadIdx.x;
    const int lane = threadIdx.x & 63;
    const int wid  = threadIdx.x >> 6;     // 0..15
    int v = (i < n) ? cnt[i] : 0;

    int incl = v;
    #pragma unroll
    for (int off = 1; off < 64; off <<= 1) {
        int t = __shfl_up(incl, off);
        if (lane >= off) incl += t;
    }
    if (lane == 63) sm[wid] = incl;
    __syncthreads();

    if (wid == 0 && lane < 16) {
        int ws = sm[lane];
        int wincl = ws;
        #pragma unroll
        for (int off = 1; off < 16; off <<= 1) {
            int t = __shfl_up(wincl, off);
            if (lane >= off) wincl += t;
        }
        sm[lane] = wincl - ws;              // exclusive wave offset
        if (lane == 15) sm[16] = wincl;     // block total
    }
    __syncthreads();

    if (i < n) rowptr[i] = sm[wid] + incl - v;   // block-local exclusive
    if (threadIdx.x == 0) blocksum[blockIdx.x] = sm[16];
}

__global__ void k_scan2(const int* __restrict__ blocksum,
                        int* __restrict__ blockoff, int nb)
{
    const int lane = threadIdx.x;          // 64 threads, 1 wave
    int running = 0;
    for (int base = 0; base < nb; base += 64) {
        int v = (base + lane < nb) ? blocksum[base + lane] : 0;
        int incl = v;
        #pragma unroll
        for (int off = 1; off < 64; off <<= 1) {
            int t = __shfl_up(incl, off);
            if (lane >= off) incl += t;
        }
        if (base + lane < nb) blockoff[base + lane] = running + incl - v;
        running += __shfl(incl, 63);
    }
}

// ---------------------------------------------------------------------------
// K4: XCD-partitioned scatter. Packed 8-B record {src, ex0:h, ex1:h} in ONE
// store -> one random write stream, 8 records per 64-B line; partition's
// 2 MB window stays in its XCD's L2 until lines fill.
// pos = local_bump(rowptr[d]) + blockoff[d>>10].
// After this kernel rowptr[d] == block-local exclusive END of segment d.
// ---------------------------------------------------------------------------
__global__ void k_scatter(const int* __restrict__ src, const int* __restrict__ dst,
                          const float* __restrict__ a_src,
                          const float* __restrict__ a_dst,
                          int* __restrict__ rowptr,
                          const int* __restrict__ blockoff,
                          int2* __restrict__ recs,
                          int nedges, int part_size)
{
    const int part  = blockIdx.x & (NPART - 1);
    const int base  = (blockIdx.x >> 3) * CHUNK;
    const int lo    = part * part_size;
    const int hi    = lo + part_size;
    #pragma unroll
    for (int k = 0; k < CHUNK / 256; ++k) {
        int i = base + k * 256 + threadIdx.x;
        if (i < nedges) {
            int d = dst[i];
            int s = src[i];                 // unconditional, coalesced
            if (d >= lo && d < hi) {
                int pos = atomicAdd(&rowptr[d], 1) + blockoff[d >> 10];
                const float2 as2 = *reinterpret_cast<const float2*>(a_src + 2 * s);
                const float2 ad2 = *reinterpret_cast<const float2*>(a_dst + 2 * d);
                unsigned e0 = f2h_bits(__expf(lrelu(as2.x + ad2.x)));
                unsigned e1 = f2h_bits(__expf(lrelu(as2.y + ad2.y)));
                int2 r;
                r.x = s;
                r.y = (int)((e1 << 16) | e0);
                recs[pos] = r;
            }
        }
    }
}

// ---------------------------------------------------------------------------
// K5: gather-accumulate. One wave per node; quarter-wave (16 lanes) per edge,
// 4 edges in flight. Lane sl owns channels sl*8..sl*8+7 (ushort8 = 16 B,
// 256 B coalesced row per quarter). Inner loop: 1 broadcast 8-B record load
// + 1 row load + 8 FMA. Self-loop = virtual edge 0. No atomics.
// ---------------------------------------------------------------------------
__global__ void k_gather(const int* __restrict__ rowptr,
                         const int* __restrict__ blockoff,
                         const int2* __restrict__ recs,
                         const float* __restrict__ a_src,
                         const float* __restrict__ a_dst,
                         const unsigned short* __restrict__ hb,
                         const float* __restrict__ bias,
                         float* __restrict__ out,
                         int nnodes)
{
    const int d = blockIdx.x * 4 + (threadIdx.x >> 6);  // wave per node
    if (d >= nnodes) return;
    const int lane = threadIdx.x & 63;
    const int q    = lane >> 4;            // quarter: which edge of the 4
    const int sl   = lane & 15;            // channel group: 8 ch each
    const int hd   = sl >> 3;              // head of those channels

    const float2 as2 = *reinterpret_cast<const float2*>(a_src + 2 * d);
    const float2 ad2 = *reinterpret_cast<const float2*>(a_dst + 2 * d);
    const float exs0 = __expf(lrelu(as2.x + ad2.x));
    const float exs1 = __expf(lrelu(as2.y + ad2.y));

    const int start = (d == 0) ? 0 : rowptr[d - 1] + blockoff[(d - 1) >> 10];
    const int end   = rowptr[d] + blockoff[d >> 10];
    const int cnt1  = end - start + 1;           // +1 for self loop

    float acc[8];
    #pragma unroll
    for (int i = 0; i < 8; ++i) acc[i] = 0.f;
    float den = 0.f;

    #pragma unroll 2
    for (int v = q; v < cnt1; v += 4) {
        int s; float ex;
        if (v == 0) {
            s = d;  ex = hd ? exs1 : exs0;
        } else {
            const int2 r = recs[start + v - 1];
            s = r.x;
            const unsigned eb = (unsigned)r.y;
            ex = h2f_bits(hd ? (unsigned short)(eb >> 16)
                             : (unsigned short)(eb & 0xFFFFu));
        }
        const ushort8_v hv = *reinterpret_cast<const ushort8_v*>(
            hb + (size_t)s * 128 + sl * 8);
        den += ex;
        #pragma unroll
        for (int i = 0; i < 8; ++i)
            acc[i] = fmaf(ex, bf2f(hv[i]), acc[i]);
    }

    // merge the four quarter accumulators
    #pragma unroll
    for (int off = 16; off <= 32; off <<= 1) {
        #pragma unroll
        for (int i = 0; i < 8; ++i) acc[i] += __shfl_xor(acc[i], off);
        den += __shfl_xor(den, off);
    }

    if (q == 0) {
        const float inv = 1.f / (den + 1e-16f);
        float4 o0, o1;
        o0.x = acc[0] * inv + bias[sl * 8 + 0];
        o0.y = acc[1] * inv + bias[sl * 8 + 1];
        o0.z = acc[2] * inv + bias[sl * 8 + 2];
        o0.w = acc[3] * inv + bias[sl * 8 + 3];
        o1.x = acc[4] * inv + bias[sl * 8 + 4];
        o1.y = acc[5] * inv + bias[sl * 8 + 5];
        o1.z = acc[6] * inv + bias[sl * 8 + 6];
        o1.w = acc[7] * inv + bias[sl * 8 + 7];
        float* op = out + (size_t)d * 128 + sl * 8;
        *reinterpret_cast<float4*>(op)     = o0;
        *reinterpret_cast<float4*>(op + 4) = o1;
    }
}

extern "C" void kernel_launch(void* const* d_in, const int* in_sizes, int n_in,
                              void* d_out, int out_size, void* d_ws, size_t ws_size,
                              hipStream_t stream) {
    const int*   edge  = (const int*)  d_in[0];   // (2,E) int32
    const float* users = (const float*)d_in[1];   // (N_USERS,64) f32
    const float* items = (const float*)d_in[2];   // (N_ITEMS,64) f32
    const float* W     = (const float*)d_in[3];   // (64,128) f32
    const float* att_s = (const float*)d_in[4];   // (2,64) f32
    const float* att_d = (const float*)d_in[5];   // (2,64) f32
    const float* bias  = (const float*)d_in[6];   // (128,) f32

    const int E       = in_sizes[0] / 2;
    const int n_users = in_sizes[1] / 64;
    const int n_items = in_sizes[2] / 64;
    const int N       = n_users + n_items;

    float* out = (float*)d_out;

    // Workspace layout (8-B alignment maintained):
    // hb (N*128 bf16) | recs (E int2) | a_src (N*2 f32) | a_dst (N*2 f32)
    // | cnt (N i32) | rowptr (N i32) | blocksum | blockoff
    char* ws = (char*)d_ws;
    unsigned short* hb = (unsigned short*)ws;
    ws += (size_t)N * 128 * sizeof(unsigned short);
    int2*  recs     = (int2*)ws;   ws += (size_t)E * sizeof(int2);
    float* a_src    = (float*)ws;  ws += (size_t)N * 2 * sizeof(float);
    float* a_dst    = (float*)ws;  ws += (size_t)N * 2 * sizeof(float);
    int*   cnt      = (int*)ws;    ws += (size_t)N * sizeof(int);
    int*   rowptr   = (int*)ws;    ws += (size_t)N * sizeof(int);
    int*   blocksum = (int*)ws;    ws += 1024 * sizeof(int);
    int*   blockoff = (int*)ws;

    const int* src = edge;
    const int* dst = edge + E;

    const int part_size   = (N + NPART - 1) / NPART;
    const int nchunks     = (E + CHUNK - 1) / CHUNK;
    const int part_grid   = nchunks * NPART;
    const int scan_blocks = (N + 1023) / 1024;

    k_node<<<N, 128, 0, stream>>>(users, items, W, att_s, att_d,
                                  hb, a_src, a_dst, cnt, n_users);

    k_hist<<<part_grid, 256, 0, stream>>>(dst, cnt, E, part_size);

    k_scan1<<<scan_blocks, 1024, 0, stream>>>(cnt, rowptr, blocksum, N);
    k_scan2<<<1, 64, 0, stream>>>(blocksum, blockoff, scan_blocks);

    k_scatter<<<part_grid, 256, 0, stream>>>(src, dst, a_src, a_dst,
                                             rowptr, blockoff, recs,
                                             E, part_size);

    k_gather<<<(N + 3) / 4, 256, 0, stream>>>(rowptr, blockoff, recs,
                                              a_src, a_dst, hb, bias, out, N);
}

// Round 7
// 326.167 us; speedup vs baseline: 5.8184x; 1.2560x over previous
//
#include <hip/hip_runtime.h>
#include <hip/hip_fp16.h>
#include <math.h>

#define NEG_SLOPE 0.2f
#define MAXB 512         // max buckets (N up to 131072); actual 259
#define BIN_E 2048       // edges per k_bin block (8 per thread, 256 thr)

typedef unsigned short ushort8_v __attribute__((ext_vector_type(8)));

__device__ __forceinline__ unsigned short f2bf(float f) {
    unsigned u = __float_as_uint(f);
    u = (u + 0x7FFFu + ((u >> 16) & 1u)) >> 16;    // round-nearest-even
    return (unsigned short)u;
}
__device__ __forceinline__ float bf2f(unsigned short b) {
    return __uint_as_float(((unsigned)b) << 16);
}
__device__ __forceinline__ float lrelu(float x) {
    return x > 0.f ? x : NEG_SLOPE * x;
}
__device__ __forceinline__ unsigned f2h_bits(float f) {
    __half_raw hr = __half_raw(__float2half_rn(f));
    return (unsigned)hr.x;
}
__device__ __forceinline__ float h2f_bits(unsigned short u) {
    __half_raw hr; hr.x = u;
    return __half2float(__half(hr));
}

// ---------------------------------------------------------------------------
// K1: per-node linear transform + attention logits; h stored bf16.
// One block (128 threads = 2 waves) per node; wave w == head w.
// ---------------------------------------------------------------------------
__global__ void k_node(const float* __restrict__ users,
                       const float* __restrict__ items,
                       const float* __restrict__ W,
                       const float* __restrict__ att_src,
                       const float* __restrict__ att_dst,
                       unsigned short* __restrict__ hb,
                       float* __restrict__ a_src,
                       float* __restrict__ a_dst,
                       int n_users)
{
    const int node = blockIdx.x;
    const int tid  = threadIdx.x;           // 0..127 == output column
    __shared__ float xs[64];

    const float* xrow = (node < n_users)
        ? (users + (size_t)node * 64)
        : (items + (size_t)(node - n_users) * 64);
    if (tid < 64) xs[tid] = xrow[tid];
    __syncthreads();

    float sum = 0.f;
    #pragma unroll
    for (int k = 0; k < 64; ++k)
        sum = fmaf(xs[k], W[k * 128 + tid], sum);   // coalesced per k

    hb[(size_t)node * 128 + tid] = f2bf(sum);

    float vs = sum * att_src[tid];
    float vd = sum * att_dst[tid];
    #pragma unroll
    for (int off = 32; off > 0; off >>= 1) {
        vs += __shfl_down(vs, off);
        vd += __shfl_down(vd, off);
    }
    const int hd = tid >> 6;                // head == wave id
    if ((tid & 63) == 0) {
        a_src[node * 2 + hd] = vs;
        a_dst[node * 2 + hd] = vd;
    }
}

// ---------------------------------------------------------------------------
// K2: bucket histogram (bucket = dst >> 8). LDS-privatized, one dst read.
// ---------------------------------------------------------------------------
__global__ void k_bhist(const int* __restrict__ dst, int* __restrict__ bcnt,
                        int nedges, int nbuckets)
{
    __shared__ int h[MAXB];
    for (int i = threadIdx.x; i < nbuckets; i += 256) h[i] = 0;
    __syncthreads();
    for (int i = blockIdx.x * 256 + threadIdx.x; i < nedges;
         i += gridDim.x * 256)
        atomicAdd(&h[dst[i] >> 8], 1);
    __syncthreads();
    for (int i = threadIdx.x; i < nbuckets; i += 256)
        if (h[i]) atomicAdd(&bcnt[i], h[i]);
}

// ---------------------------------------------------------------------------
// K3: exclusive scan of bcnt -> bucket_base AND tails (bump cursors for
// k_bin). Single wave. Also writes rowptr[N] = E.
// ---------------------------------------------------------------------------
__global__ void k_bscan(const int* __restrict__ bcnt,
                        int* __restrict__ bucket_base,
                        int* __restrict__ tails,
                        int* __restrict__ rowptr,
                        int nbuckets, int N, int E)
{
    const int lane = threadIdx.x;          // 64 threads
    int running = 0;
    for (int base = 0; base < nbuckets; base += 64) {
        int idx = base + lane;
        int v = (idx < nbuckets) ? bcnt[idx] : 0;
        int incl = v;
        #pragma unroll
        for (int off = 1; off < 64; off <<= 1) {
            int t = __shfl_up(incl, off);
            if (lane >= off) incl += t;
        }
        if (idx < nbuckets) {
            int ex = running + incl - v;
            bucket_base[idx] = ex;
            tails[idx]       = ex;
        }
        running += __shfl(incl, 63);
    }
    if (lane == 0) rowptr[N] = E;
}

// ---------------------------------------------------------------------------
// K4: bin pass. Each block: read 2048 edges ONCE, build packed records
//   rec.x = (ex1_h<<16)|ex0_h   (fp16 attention weights, exp precomputed)
//   rec.y = src | (dst&255)<<17 (src<2^17; dlow kept for refine pass)
// LDS counting-sort by bucket, then per-bucket: one atomic tail bump +
// contiguous burst write. Lines at tails fill immediately -> write ~= payload.
// ---------------------------------------------------------------------------
__global__ void k_bin(const int* __restrict__ src, const int* __restrict__ dst,
                      const float* __restrict__ a_src,
                      const float* __restrict__ a_dst,
                      int* __restrict__ tails,
                      int2* __restrict__ stage_g,
                      int nedges, int nbuckets)
{
    __shared__ int cnt[MAXB];
    __shared__ int runoff[MAXB];
    __shared__ int cursor[MAXB];
    __shared__ int runbase[MAXB];
    __shared__ int2 stage[BIN_E];
    __shared__ unsigned short sb[BIN_E];

    const int tid  = threadIdx.x;
    const int lane = tid & 63;
    const int wid  = tid >> 6;
    const int base = blockIdx.x * BIN_E;
    const int nvalid = min(BIN_E, nedges - base);

    for (int i = tid; i < nbuckets; i += 256) cnt[i] = 0;
    __syncthreads();

    int2 myrec[BIN_E / 256];
    int  myb[BIN_E / 256];
    #pragma unroll
    for (int k = 0; k < BIN_E / 256; ++k) {
        int i = base + k * 256 + tid;
        if (i < nedges) {
            int d = dst[i];
            int s = src[i];
            const float2 as2 = *reinterpret_cast<const float2*>(a_src + 2 * s);
            const float2 ad2 = *reinterpret_cast<const float2*>(a_dst + 2 * d);
            unsigned e0 = f2h_bits(__expf(lrelu(as2.x + ad2.x)));
            unsigned e1 = f2h_bits(__expf(lrelu(as2.y + ad2.y)));
            myrec[k].x = (int)((e1 << 16) | e0);
            myrec[k].y = s | ((d & 255) << 17);
            int b = d >> 8;
            myb[k] = b;
            atomicAdd(&cnt[b], 1);
        } else {
            myb[k] = -1;
        }
    }
    __syncthreads();

    // wave 0: exclusive scan cnt -> runoff
    if (wid == 0) {
        int running = 0;
        for (int b2 = 0; b2 < nbuckets; b2 += 64) {
            int idx = b2 + lane;
            int v = (idx < nbuckets) ? cnt[idx] : 0;
            int incl = v;
            #pragma unroll
            for (int off = 1; off < 64; off <<= 1) {
                int t = __shfl_up(incl, off);
                if (lane >= off) incl += t;
            }
            if (idx < nbuckets) runoff[idx] = running + incl - v;
            running += __shfl(incl, 63);
        }
    }
    __syncthreads();

    for (int i = tid; i < nbuckets; i += 256) cursor[i] = runoff[i];
    __syncthreads();

    // place records into bucket-sorted LDS staging
    #pragma unroll
    for (int k = 0; k < BIN_E / 256; ++k) {
        if (myb[k] >= 0) {
            int pos = atomicAdd(&cursor[myb[k]], 1);
            stage[pos] = myrec[k];
            sb[pos] = (unsigned short)myb[k];
        }
    }

    // claim global runs
    for (int i = tid; i < nbuckets; i += 256)
        if (cnt[i] > 0) runbase[i] = atomicAdd(&tails[i], cnt[i]);
    __syncthreads();

    // flush: piecewise-contiguous global writes
    for (int i = tid; i < nvalid; i += 256) {
        int b = sb[i];
        stage_g[runbase[b] + (i - runoff[b])] = stage[i];
    }
}

// ---------------------------------------------------------------------------
// K5: refine. One block per bucket (256 nodes): histogram the bucket's
// records over 256 node slots (per-node rowptr falls out free), scan,
// scatter into exact per-dst CSR order. All writes land in one ~62 KB
// region within one block's lifetime -> no write amplification.
// ---------------------------------------------------------------------------
__global__ void k_refine(const int2* __restrict__ stage_g,
                         const int* __restrict__ bucket_base,
                         int* __restrict__ rowptr,
                         int2* __restrict__ recs,
                         int N, int E, int nbuckets)
{
    const int b   = blockIdx.x;
    const int tid = threadIdx.x;
    const int lane = tid & 63;
    const int wid  = tid >> 6;
    const int lo = bucket_base[b];
    const int hi = (b + 1 < nbuckets) ? bucket_base[b + 1] : E;
    const int node0  = b << 8;
    const int nnodes = min(256, N - node0);

    __shared__ int cnt[256];
    __shared__ int off[256];
    __shared__ int cursor[256];

    if (tid < 256) cnt[tid] = 0;
    __syncthreads();

    for (int i = lo + tid; i < hi; i += 256) {
        int dlow = (stage_g[i].y >> 17) & 255;
        atomicAdd(&cnt[dlow], 1);
    }
    __syncthreads();

    if (wid == 0) {
        int running = 0;
        for (int b2 = 0; b2 < 256; b2 += 64) {
            int idx = b2 + lane;
            int v = cnt[idx];
            int incl = v;
            #pragma unroll
            for (int o = 1; o < 64; o <<= 1) {
                int t = __shfl_up(incl, o);
                if (lane >= o) incl += t;
            }
            off[idx] = running + incl - v;
            running += __shfl(incl, 63);
        }
    }
    __syncthreads();

    if (tid < nnodes) rowptr[node0 + tid] = lo + off[tid];
    if (tid < 256) cursor[tid] = lo + off[tid];
    __syncthreads();

    for (int i = lo + tid; i < hi; i += 256) {
        int2 r = stage_g[i];
        int dlow = (r.y >> 17) & 255;
        int pos = atomicAdd(&cursor[dlow], 1);
        recs[pos] = r;
    }
}

// ---------------------------------------------------------------------------
// K6: gather-accumulate. One wave per node; quarter-wave (16 lanes) per
// edge, 4 edges in flight. Lane sl owns channels sl*8..sl*8+7 (ushort8 =
// 16 B, 256 B coalesced row per quarter). Self-loop = virtual edge 0.
// ---------------------------------------------------------------------------
__global__ void k_gather(const int* __restrict__ rowptr,
                         const int2* __restrict__ recs,
                         const float* __restrict__ a_src,
                         const float* __restrict__ a_dst,
                         const unsigned short* __restrict__ hb,
                         const float* __restrict__ bias,
                         float* __restrict__ out,
                         int nnodes)
{
    const int d = blockIdx.x * 4 + (threadIdx.x >> 6);  // wave per node
    if (d >= nnodes) return;
    const int lane = threadIdx.x & 63;
    const int q    = lane >> 4;            // quarter: which edge of the 4
    const int sl   = lane & 15;            // channel group: 8 ch each
    const int hd   = sl >> 3;              // head of those channels

    const float2 as2 = *reinterpret_cast<const float2*>(a_src + 2 * d);
    const float2 ad2 = *reinterpret_cast<const float2*>(a_dst + 2 * d);
    const float exs0 = __expf(lrelu(as2.x + ad2.x));
    const float exs1 = __expf(lrelu(as2.y + ad2.y));

    const int start = rowptr[d];
    const int cnt1  = rowptr[d + 1] - start + 1;   // +1 for self loop

    float acc[8];
    #pragma unroll
    for (int i = 0; i < 8; ++i) acc[i] = 0.f;
    float den = 0.f;

    #pragma unroll 2
    for (int v = q; v < cnt1; v += 4) {
        int s; float ex;
        if (v == 0) {
            s = d;  ex = hd ? exs1 : exs0;
        } else {
            const int2 r = recs[start + v - 1];
            s = r.y & 0x1FFFF;
            const unsigned eb = (unsigned)r.x;
            ex = h2f_bits(hd ? (unsigned short)(eb >> 16)
                             : (unsigned short)(eb & 0xFFFFu));
        }
        const ushort8_v hv = *reinterpret_cast<const ushort8_v*>(
            hb + (size_t)s * 128 + sl * 8);
        den += ex;
        #pragma unroll
        for (int i = 0; i < 8; ++i)
            acc[i] = fmaf(ex, bf2f(hv[i]), acc[i]);
    }

    // merge the four quarter accumulators
    #pragma unroll
    for (int off = 16; off <= 32; off <<= 1) {
        #pragma unroll
        for (int i = 0; i < 8; ++i) acc[i] += __shfl_xor(acc[i], off);
        den += __shfl_xor(den, off);
    }

    if (q == 0) {
        const float inv = 1.f / (den + 1e-16f);
        float4 o0, o1;
        o0.x = acc[0] * inv + bias[sl * 8 + 0];
        o0.y = acc[1] * inv + bias[sl * 8 + 1];
        o0.z = acc[2] * inv + bias[sl * 8 + 2];
        o0.w = acc[3] * inv + bias[sl * 8 + 3];
        o1.x = acc[4] * inv + bias[sl * 8 + 4];
        o1.y = acc[5] * inv + bias[sl * 8 + 5];
        o1.z = acc[6] * inv + bias[sl * 8 + 6];
        o1.w = acc[7] * inv + bias[sl * 8 + 7];
        float* op = out + (size_t)d * 128 + sl * 8;
        *reinterpret_cast<float4*>(op)     = o0;
        *reinterpret_cast<float4*>(op + 4) = o1;
    }
}

extern "C" void kernel_launch(void* const* d_in, const int* in_sizes, int n_in,
                              void* d_out, int out_size, void* d_ws, size_t ws_size,
                              hipStream_t stream) {
    const int*   edge  = (const int*)  d_in[0];   // (2,E) int32
    const float* users = (const float*)d_in[1];   // (N_USERS,64) f32
    const float* items = (const float*)d_in[2];   // (N_ITEMS,64) f32
    const float* W     = (const float*)d_in[3];   // (64,128) f32
    const float* att_s = (const float*)d_in[4];   // (2,64) f32
    const float* att_d = (const float*)d_in[5];   // (2,64) f32
    const float* bias  = (const float*)d_in[6];   // (128,) f32

    const int E       = in_sizes[0] / 2;
    const int n_users = in_sizes[1] / 64;
    const int n_items = in_sizes[2] / 64;
    const int N       = n_users + n_items;
    const int nbuckets = (N + 255) >> 8;          // 259

    float* out = (float*)d_out;

    // Workspace layout (8-B alignment maintained):
    // hb (N*128 bf16) | stage (E int2) | recs (E int2) | a_src | a_dst
    // | rowptr (N+1) | bcnt | bucket_base | tails
    char* ws = (char*)d_ws;
    unsigned short* hb = (unsigned short*)ws;
    ws += (size_t)N * 128 * sizeof(unsigned short);
    int2*  stage    = (int2*)ws;   ws += (size_t)E * sizeof(int2);
    int2*  recs     = (int2*)ws;   ws += (size_t)E * sizeof(int2);
    float* a_src    = (float*)ws;  ws += (size_t)N * 2 * sizeof(float);
    float* a_dst    = (float*)ws;  ws += (size_t)N * 2 * sizeof(float);
    int*   rowptr   = (int*)ws;    ws += (size_t)(N + 1) * sizeof(int);
    int*   bcnt     = (int*)ws;    ws += MAXB * sizeof(int);
    int*   bucket_base = (int*)ws; ws += MAXB * sizeof(int);
    int*   tails    = (int*)ws;

    const int* src = edge;
    const int* dst = edge + E;

    hipMemsetAsync(bcnt, 0, MAXB * sizeof(int), stream);

    k_node<<<N, 128, 0, stream>>>(users, items, W, att_s, att_d,
                                  hb, a_src, a_dst, n_users);

    k_bhist<<<512, 256, 0, stream>>>(dst, bcnt, E, nbuckets);

    k_bscan<<<1, 64, 0, stream>>>(bcnt, bucket_base, tails, rowptr,
                                  nbuckets, N, E);

    k_bin<<<(E + BIN_E - 1) / BIN_E, 256, 0, stream>>>(
        src, dst, a_src, a_dst, tails, stage, E, nbuckets);

    k_refine<<<nbuckets, 256, 0, stream>>>(stage, bucket_base, rowptr,
                                           recs, N, E, nbuckets);

    k_gather<<<(N + 3) / 4, 256, 0, stream>>>(rowptr, recs, a_src, a_dst,
                                              hb, bias, out, N);
}

// Round 8
// 301.096 us; speedup vs baseline: 6.3029x; 1.0833x over previous
//
#include <hip/hip_runtime.h>
#include <hip/hip_fp16.h>
#include <math.h>

#define NEG_SLOPE 0.2f
#define MAXB 512         // max buckets (N up to 131072); actual 259
#define BIN_E 2048       // edges per k_bin block (8 per thread, 256 thr)

typedef unsigned short ushort8_v __attribute__((ext_vector_type(8)));
typedef short  short8_v  __attribute__((ext_vector_type(8)));
typedef float  float4_v  __attribute__((ext_vector_type(4)));

__device__ __forceinline__ unsigned short f2bf(float f) {
    unsigned u = __float_as_uint(f);
    u = (u + 0x7FFFu + ((u >> 16) & 1u)) >> 16;    // round-nearest-even
    return (unsigned short)u;
}
__device__ __forceinline__ float bf2f(unsigned short b) {
    return __uint_as_float(((unsigned)b) << 16);
}
__device__ __forceinline__ float lrelu(float x) {
    return x > 0.f ? x : NEG_SLOPE * x;
}
__device__ __forceinline__ unsigned f2h_bits(float f) {
    __half_raw hr = __half_raw(__float2half_rn(f));
    return (unsigned)hr.x;
}
__device__ __forceinline__ float h2f_bits(unsigned short u) {
    __half_raw hr; hr.x = u;
    return __half2float(__half(hr));
}

// ---------------------------------------------------------------------------
// K1: node transform via MFMA.  h = x@W in bf16 MFMA (f32 accum), plus
// attention logits a_src/a_dst via per-quad shfl reduction.
// Block = 256 thr = 4 waves; wave = 16-node tile (64 nodes/block).
// Layouts (verified, m89/m91/m120): A[m=lane&15][k=quad*8+j],
// B[k=quad*8+j][n=lane&15], C: col=lane&15, row=quad*4+reg.
// W re-read per block is 4x32 KB (vs 32 KB/node before): L2 traffic
// 2.1 GB -> ~170 MB, which was k_node's 80 us.
// ---------------------------------------------------------------------------
__global__ void k_node(const float* __restrict__ users,
                       const float* __restrict__ items,
                       const float* __restrict__ W,
                       const float* __restrict__ att_src,
                       const float* __restrict__ att_dst,
                       unsigned short* __restrict__ hb,
                       float* __restrict__ a_src,
                       float* __restrict__ a_dst,
                       int n_users, int N)
{
    const int wid  = threadIdx.x >> 6;       // wave 0..3
    const int lane = threadIdx.x & 63;
    const int quad = lane >> 4;              // 0..3
    const int l16  = lane & 15;
    const int tb   = blockIdx.x * 64 + wid * 16;   // tile base node

    // B fragments: bfrag[t][h2] holds W[k = h2*32+quad*8+j][t*16 + l16]
    short8_v bfrag[8][2];
    #pragma unroll
    for (int t = 0; t < 8; ++t)
        #pragma unroll
        for (int h2 = 0; h2 < 2; ++h2)
            #pragma unroll
            for (int j = 0; j < 8; ++j)
                bfrag[t][h2][j] = (short)f2bf(
                    W[(h2 * 32 + quad * 8 + j) * 128 + t * 16 + l16]);

    // att vectors for this lane's column in each tile
    float atts[8], attd[8];
    #pragma unroll
    for (int t = 0; t < 8; ++t) {
        atts[t] = att_src[t * 16 + l16];
        attd[t] = att_dst[t * 16 + l16];
    }

    // A fragments: row = tb + l16, k = quad*8+j (+32 for second half)
    const int arow = tb + l16;
    short8_v a0 = (short8_v)0, a1 = (short8_v)0;
    if (arow < N) {
        const float* xr = (arow < n_users)
            ? (users + (size_t)arow * 64)
            : (items + (size_t)(arow - n_users) * 64);
        const float4_v x0 = *reinterpret_cast<const float4_v*>(xr + quad * 8);
        const float4_v x1 = *reinterpret_cast<const float4_v*>(xr + quad * 8 + 4);
        const float4_v x2 = *reinterpret_cast<const float4_v*>(xr + 32 + quad * 8);
        const float4_v x3 = *reinterpret_cast<const float4_v*>(xr + 32 + quad * 8 + 4);
        #pragma unroll
        for (int j = 0; j < 4; ++j) {
            a0[j]     = (short)f2bf(x0[j]);
            a0[j + 4] = (short)f2bf(x1[j]);
            a1[j]     = (short)f2bf(x2[j]);
            a1[j + 4] = (short)f2bf(x3[j]);
        }
    }

    float4_v acc[8];
    #pragma unroll
    for (int t = 0; t < 8; ++t) {
        acc[t] = (float4_v)0.f;
        acc[t] = __builtin_amdgcn_mfma_f32_16x16x32_bf16(a0, bfrag[t][0], acc[t], 0, 0, 0);
        acc[t] = __builtin_amdgcn_mfma_f32_16x16x32_bf16(a1, bfrag[t][1], acc[t], 0, 0, 0);
    }

    // epilogue: write hb (bf16) + per-head attention dot products
    const int wrow0 = tb + quad * 4;
    float s0[4] = {0,0,0,0}, s1[4] = {0,0,0,0};
    float d0[4] = {0,0,0,0}, d1[4] = {0,0,0,0};
    #pragma unroll
    for (int t = 0; t < 8; ++t) {
        #pragma unroll
        for (int r = 0; r < 4; ++r) {
            const float v = acc[t][r];
            if (t < 4) { s0[r] = fmaf(v, atts[t], s0[r]);
                         d0[r] = fmaf(v, attd[t], d0[r]); }
            else       { s1[r] = fmaf(v, atts[t], s1[r]);
                         d1[r] = fmaf(v, attd[t], d1[r]); }
            const int row = wrow0 + r;
            if (row < N)
                hb[(size_t)row * 128 + t * 16 + l16] = f2bf(v);
        }
    }

    // reduce the 16 lanes of each quad (cols) -> per-row logit sums
    #pragma unroll
    for (int off = 1; off < 16; off <<= 1) {
        #pragma unroll
        for (int r = 0; r < 4; ++r) {
            s0[r] += __shfl_xor(s0[r], off);
            s1[r] += __shfl_xor(s1[r], off);
            d0[r] += __shfl_xor(d0[r], off);
            d1[r] += __shfl_xor(d1[r], off);
        }
    }
    if (l16 == 0) {
        #pragma unroll
        for (int r = 0; r < 4; ++r) {
            const int row = wrow0 + r;
            if (row < N) {
                a_src[row * 2]     = s0[r];
                a_src[row * 2 + 1] = s1[r];
                a_dst[row * 2]     = d0[r];
                a_dst[row * 2 + 1] = d1[r];
            }
        }
    }
}

// ---------------------------------------------------------------------------
// K2: bucket histogram (bucket = dst >> 8). LDS-privatized, one dst read.
// ---------------------------------------------------------------------------
__global__ void k_bhist(const int* __restrict__ dst, int* __restrict__ bcnt,
                        int nedges, int nbuckets)
{
    __shared__ int h[MAXB];
    for (int i = threadIdx.x; i < nbuckets; i += 256) h[i] = 0;
    __syncthreads();
    for (int i = blockIdx.x * 256 + threadIdx.x; i < nedges;
         i += gridDim.x * 256)
        atomicAdd(&h[dst[i] >> 8], 1);
    __syncthreads();
    for (int i = threadIdx.x; i < nbuckets; i += 256)
        if (h[i]) atomicAdd(&bcnt[i], h[i]);
}

// ---------------------------------------------------------------------------
// K3: exclusive scan of bcnt -> bucket_base AND tails (bump cursors for
// k_bin). Single wave. Also writes rowptr[N] = E.
// ---------------------------------------------------------------------------
__global__ void k_bscan(const int* __restrict__ bcnt,
                        int* __restrict__ bucket_base,
                        int* __restrict__ tails,
                        int* __restrict__ rowptr,
                        int nbuckets, int N, int E)
{
    const int lane = threadIdx.x;          // 64 threads
    int running = 0;
    for (int base = 0; base < nbuckets; base += 64) {
        int idx = base + lane;
        int v = (idx < nbuckets) ? bcnt[idx] : 0;
        int incl = v;
        #pragma unroll
        for (int off = 1; off < 64; off <<= 1) {
            int t = __shfl_up(incl, off);
            if (lane >= off) incl += t;
        }
        if (idx < nbuckets) {
            int ex = running + incl - v;
            bucket_base[idx] = ex;
            tails[idx]       = ex;
        }
        running += __shfl(incl, 63);
    }
    if (lane == 0) rowptr[N] = E;
}

// ---------------------------------------------------------------------------
// K4: bin pass. Each block: read 2048 edges ONCE, build packed records
//   rec.x = (ex1_h<<16)|ex0_h   (fp16 attention weights, exp precomputed)
//   rec.y = src | (dst&255)<<17 (src<2^17; dlow kept for refine pass)
// LDS counting-sort by bucket, then per-bucket: one atomic tail bump +
// contiguous burst write. Lines at tails fill immediately -> write ~= payload.
// ---------------------------------------------------------------------------
__global__ void k_bin(const int* __restrict__ src, const int* __restrict__ dst,
                      const float* __restrict__ a_src,
                      const float* __restrict__ a_dst,
                      int* __restrict__ tails,
                      int2* __restrict__ stage_g,
                      int nedges, int nbuckets)
{
    __shared__ int cnt[MAXB];
    __shared__ int runoff[MAXB];
    __shared__ int cursor[MAXB];
    __shared__ int runbase[MAXB];
    __shared__ int2 stage[BIN_E];
    __shared__ unsigned short sb[BIN_E];

    const int tid  = threadIdx.x;
    const int lane = tid & 63;
    const int wid  = tid >> 6;
    const int base = blockIdx.x * BIN_E;
    const int nvalid = min(BIN_E, nedges - base);

    for (int i = tid; i < nbuckets; i += 256) cnt[i] = 0;
    __syncthreads();

    int2 myrec[BIN_E / 256];
    int  myb[BIN_E / 256];
    #pragma unroll
    for (int k = 0; k < BIN_E / 256; ++k) {
        int i = base + k * 256 + tid;
        if (i < nedges) {
            int d = dst[i];
            int s = src[i];
            const float2 as2 = *reinterpret_cast<const float2*>(a_src + 2 * s);
            const float2 ad2 = *reinterpret_cast<const float2*>(a_dst + 2 * d);
            unsigned e0 = f2h_bits(__expf(lrelu(as2.x + ad2.x)));
            unsigned e1 = f2h_bits(__expf(lrelu(as2.y + ad2.y)));
            myrec[k].x = (int)((e1 << 16) | e0);
            myrec[k].y = s | ((d & 255) << 17);
            int b = d >> 8;
            myb[k] = b;
            atomicAdd(&cnt[b], 1);
        } else {
            myb[k] = -1;
        }
    }
    __syncthreads();

    // wave 0: exclusive scan cnt -> runoff
    if (wid == 0) {
        int running = 0;
        for (int b2 = 0; b2 < nbuckets; b2 += 64) {
            int idx = b2 + lane;
            int v = (idx < nbuckets) ? cnt[idx] : 0;
            int incl = v;
            #pragma unroll
            for (int off = 1; off < 64; off <<= 1) {
                int t = __shfl_up(incl, off);
                if (lane >= off) incl += t;
            }
            if (idx < nbuckets) runoff[idx] = running + incl - v;
            running += __shfl(incl, 63);
        }
    }
    __syncthreads();

    for (int i = tid; i < nbuckets; i += 256) cursor[i] = runoff[i];
    __syncthreads();

    // place records into bucket-sorted LDS staging
    #pragma unroll
    for (int k = 0; k < BIN_E / 256; ++k) {
        if (myb[k] >= 0) {
            int pos = atomicAdd(&cursor[myb[k]], 1);
            stage[pos] = myrec[k];
            sb[pos] = (unsigned short)myb[k];
        }
    }

    // claim global runs
    for (int i = tid; i < nbuckets; i += 256)
        if (cnt[i] > 0) runbase[i] = atomicAdd(&tails[i], cnt[i]);
    __syncthreads();

    // flush: piecewise-contiguous global writes
    for (int i = tid; i < nvalid; i += 256) {
        int b = sb[i];
        stage_g[runbase[b] + (i - runoff[b])] = stage[i];
    }
}

// ---------------------------------------------------------------------------
// K5: refine. One block per bucket (256 nodes): histogram the bucket's
// records over 256 node slots (per-node rowptr falls out free), scan,
// scatter records into exact per-dst CSR order.
// ---------------------------------------------------------------------------
__global__ void k_refine(const int2* __restrict__ stage_g,
                         const int* __restrict__ bucket_base,
                         int* __restrict__ rowptr,
                         int2* __restrict__ recs,
                         int N, int E, int nbuckets)
{
    const int b   = blockIdx.x;
    const int tid = threadIdx.x;
    const int lane = tid & 63;
    const int wid  = tid >> 6;
    const int lo = bucket_base[b];
    const int hi = (b + 1 < nbuckets) ? bucket_base[b + 1] : E;
    const int node0  = b << 8;
    const int nnodes = min(256, N - node0);

    __shared__ int cnt[256];
    __shared__ int off[256];
    __shared__ int cursor[256];

    if (tid < 256) cnt[tid] = 0;
    __syncthreads();

    for (int i = lo + tid; i < hi; i += 256) {
        int dlow = (stage_g[i].y >> 17) & 255;
        atomicAdd(&cnt[dlow], 1);
    }
    __syncthreads();

    if (wid == 0) {
        int running = 0;
        for (int b2 = 0; b2 < 256; b2 += 64) {
            int idx = b2 + lane;
            int v = cnt[idx];
            int incl = v;
            #pragma unroll
            for (int o = 1; o < 64; o <<= 1) {
                int t = __shfl_up(incl, o);
                if (lane >= o) incl += t;
            }
            off[idx] = running + incl - v;
            running += __shfl(incl, 63);
        }
    }
    __syncthreads();

    if (tid < nnodes) rowptr[node0 + tid] = lo + off[tid];
    if (tid < 256) cursor[tid] = lo + off[tid];
    __syncthreads();

    for (int i = lo + tid; i < hi; i += 256) {
        int2 r = stage_g[i];
        int dlow = (r.y >> 17) & 255;
        int pos = atomicAdd(&cursor[dlow], 1);
        recs[pos] = r;
    }
}

// ---------------------------------------------------------------------------
// K6: gather-accumulate. One wave per node; quarter-wave (16 lanes) per
// edge, 4 edges in flight. Lane sl owns channels sl*8..sl*8+7 (ushort8 =
// 16 B, 256 B coalesced row per quarter). Self-loop = virtual edge 0.
// ---------------------------------------------------------------------------
__global__ void k_gather(const int* __restrict__ rowptr,
                         const int2* __restrict__ recs,
                         const float* __restrict__ a_src,
                         const float* __restrict__ a_dst,
                         const unsigned short* __restrict__ hb,
                         const float* __restrict__ bias,
                         float* __restrict__ out,
                         int nnodes)
{
    const int d = blockIdx.x * 4 + (threadIdx.x >> 6);  // wave per node
    if (d >= nnodes) return;
    const int lane = threadIdx.x & 63;
    const int q    = lane >> 4;            // quarter: which edge of the 4
    const int sl   = lane & 15;            // channel group: 8 ch each
    const int hd   = sl >> 3;              // head of those channels

    const float2 as2 = *reinterpret_cast<const float2*>(a_src + 2 * d);
    const float2 ad2 = *reinterpret_cast<const float2*>(a_dst + 2 * d);
    const float exs0 = __expf(lrelu(as2.x + ad2.x));
    const float exs1 = __expf(lrelu(as2.y + ad2.y));

    const int start = rowptr[d];
    const int cnt1  = rowptr[d + 1] - start + 1;   // +1 for self loop

    float acc[8];
    #pragma unroll
    for (int i = 0; i < 8; ++i) acc[i] = 0.f;
    float den = 0.f;

    #pragma unroll 2
    for (int v = q; v < cnt1; v += 4) {
        int s; float ex;
        if (v == 0) {
            s = d;  ex = hd ? exs1 : exs0;
        } else {
            const int2 r = recs[start + v - 1];
            s = r.y & 0x1FFFF;
            const unsigned eb = (unsigned)r.x;
            ex = h2f_bits(hd ? (unsigned short)(eb >> 16)
                             : (unsigned short)(eb & 0xFFFFu));
        }
        const ushort8_v hv = *reinterpret_cast<const ushort8_v*>(
            hb + (size_t)s * 128 + sl * 8);
        den += ex;
        #pragma unroll
        for (int i = 0; i < 8; ++i)
            acc[i] = fmaf(ex, bf2f(hv[i]), acc[i]);
    }

    // merge the four quarter accumulators
    #pragma unroll
    for (int off = 16; off <= 32; off <<= 1) {
        #pragma unroll
        for (int i = 0; i < 8; ++i) acc[i] += __shfl_xor(acc[i], off);
        den += __shfl_xor(den, off);
    }

    if (q == 0) {
        const float inv = 1.f / (den + 1e-16f);
        float4 o0, o1;
        o0.x = acc[0] * inv + bias[sl * 8 + 0];
        o0.y = acc[1] * inv + bias[sl * 8 + 1];
        o0.z = acc[2] * inv + bias[sl * 8 + 2];
        o0.w = acc[3] * inv + bias[sl * 8 + 3];
        o1.x = acc[4] * inv + bias[sl * 8 + 4];
        o1.y = acc[5] * inv + bias[sl * 8 + 5];
        o1.z = acc[6] * inv + bias[sl * 8 + 6];
        o1.w = acc[7] * inv + bias[sl * 8 + 7];
        float* op = out + (size_t)d * 128 + sl * 8;
        *reinterpret_cast<float4*>(op)     = o0;
        *reinterpret_cast<float4*>(op + 4) = o1;
    }
}

extern "C" void kernel_launch(void* const* d_in, const int* in_sizes, int n_in,
                              void* d_out, int out_size, void* d_ws, size_t ws_size,
                              hipStream_t stream) {
    const int*   edge  = (const int*)  d_in[0];   // (2,E) int32
    const float* users = (const float*)d_in[1];   // (N_USERS,64) f32
    const float* items = (const float*)d_in[2];   // (N_ITEMS,64) f32
    const float* W     = (const float*)d_in[3];   // (64,128) f32
    const float* att_s = (const float*)d_in[4];   // (2,64) f32
    const float* att_d = (const float*)d_in[5];   // (2,64) f32
    const float* bias  = (const float*)d_in[6];   // (128,) f32

    const int E       = in_sizes[0] / 2;
    const int n_users = in_sizes[1] / 64;
    const int n_items = in_sizes[2] / 64;
    const int N       = n_users + n_items;
    const int nbuckets = (N + 255) >> 8;          // 259

    float* out = (float*)d_out;

    // Workspace layout (8-B alignment maintained):
    // hb (N*128 bf16) | stage (E int2) | recs (E int2) | a_src | a_dst
    // | rowptr (N+1) | bcnt | bucket_base | tails
    char* ws = (char*)d_ws;
    unsigned short* hb = (unsigned short*)ws;
    ws += (size_t)N * 128 * sizeof(unsigned short);
    int2*  stage    = (int2*)ws;   ws += (size_t)E * sizeof(int2);
    int2*  recs     = (int2*)ws;   ws += (size_t)E * sizeof(int2);
    float* a_src    = (float*)ws;  ws += (size_t)N * 2 * sizeof(float);
    float* a_dst    = (float*)ws;  ws += (size_t)N * 2 * sizeof(float);
    int*   rowptr   = (int*)ws;    ws += (size_t)(N + 1) * sizeof(int);
    int*   bcnt     = (int*)ws;    ws += MAXB * sizeof(int);
    int*   bucket_base = (int*)ws; ws += MAXB * sizeof(int);
    int*   tails    = (int*)ws;

    const int* src = edge;
    const int* dst = edge + E;

    hipMemsetAsync(bcnt, 0, MAXB * sizeof(int), stream);

    k_node<<<(N + 63) / 64, 256, 0, stream>>>(users, items, W, att_s, att_d,
                                              hb, a_src, a_dst, n_users, N);

    k_bhist<<<512, 256, 0, stream>>>(dst, bcnt, E, nbuckets);

    k_bscan<<<1, 64, 0, stream>>>(bcnt, bucket_base, tails, rowptr,
                                  nbuckets, N, E);

    k_bin<<<(E + BIN_E - 1) / BIN_E, 256, 0, stream>>>(
        src, dst, a_src, a_dst, tails, stage, E, nbuckets);

    k_refine<<<nbuckets, 256, 0, stream>>>(stage, bucket_base, rowptr,
                                           recs, N, E, nbuckets);

    k_gather<<<(N + 3) / 4, 256, 0, stream>>>(rowptr, recs, a_src, a_dst,
                                              hb, bias, out, N);
}

// Round 9
// 282.688 us; speedup vs baseline: 6.7133x; 1.0651x over previous
//
#include <hip/hip_runtime.h>
#include <hip/hip_fp16.h>
#include <math.h>

#define NEG_SLOPE 0.2f
#define MAXB 512         // max buckets (N up to 131072); actual 259
#define BIN_E 2048       // edges per k_bin block
#define HIST_BLKS 512    // histogram blocks fused into k_node dispatch

typedef unsigned short ushort8_v __attribute__((ext_vector_type(8)));
typedef short  short8_v  __attribute__((ext_vector_type(8)));
typedef float  float4_v  __attribute__((ext_vector_type(4)));

__device__ __forceinline__ unsigned short f2bf(float f) {
    unsigned u = __float_as_uint(f);
    u = (u + 0x7FFFu + ((u >> 16) & 1u)) >> 16;    // round-nearest-even
    return (unsigned short)u;
}
__device__ __forceinline__ float bf2f(unsigned short b) {
    return __uint_as_float(((unsigned)b) << 16);
}
__device__ __forceinline__ float lrelu(float x) {
    return x > 0.f ? x : NEG_SLOPE * x;
}
__device__ __forceinline__ unsigned f2h_bits(float f) {
    __half_raw hr = __half_raw(__float2half_rn(f));
    return (unsigned)hr.x;
}
__device__ __forceinline__ float h2f_bits(unsigned short u) {
    __half_raw hr; hr.x = u;
    return __half2float(__half(hr));
}

// ---------------------------------------------------------------------------
// K1 (fused): blocks [0, HIST_BLKS): bucket histogram of dst (BW-bound,
// streams while MFMA blocks compute). Blocks [HIST_BLKS, ...): node
// transform via MFMA (h = x@W bf16, f32 accum) + attention logits.
// Node part: 256 thr = 4 waves; wave = 16-node tile (64 nodes/block).
// Layouts (verified m89/m91/m120): A[m=lane&15][k=quad*8+j],
// B[k=quad*8+j][n=lane&15], C: col=lane&15, row=quad*4+reg.
// ---------------------------------------------------------------------------
__global__ void k_node_hist(const float* __restrict__ users,
                            const float* __restrict__ items,
                            const float* __restrict__ W,
                            const float* __restrict__ att_src,
                            const float* __restrict__ att_dst,
                            unsigned short* __restrict__ hb,
                            float* __restrict__ a_src,
                            float* __restrict__ a_dst,
                            const int* __restrict__ dst,
                            int* __restrict__ bcnt,
                            int nedges, int nbuckets,
                            int n_users, int N)
{
    __shared__ int hsh[MAXB];

    if (blockIdx.x < HIST_BLKS) {
        // ---- histogram part ----
        for (int i = threadIdx.x; i < nbuckets; i += 256) hsh[i] = 0;
        __syncthreads();
        for (int i = blockIdx.x * 256 + threadIdx.x; i < nedges;
             i += HIST_BLKS * 256)
            atomicAdd(&hsh[dst[i] >> 8], 1);
        __syncthreads();
        for (int i = threadIdx.x; i < nbuckets; i += 256)
            if (hsh[i]) atomicAdd(&bcnt[i], hsh[i]);
        return;
    }

    // ---- node transform part ----
    const int blk  = blockIdx.x - HIST_BLKS;
    const int wid  = threadIdx.x >> 6;       // wave 0..3
    const int lane = threadIdx.x & 63;
    const int quad = lane >> 4;              // 0..3
    const int l16  = lane & 15;
    const int tb   = blk * 64 + wid * 16;    // tile base node

    // B fragments: bfrag[t][h2] holds W[k = h2*32+quad*8+j][t*16 + l16]
    short8_v bfrag[8][2];
    #pragma unroll
    for (int t = 0; t < 8; ++t)
        #pragma unroll
        for (int h2 = 0; h2 < 2; ++h2)
            #pragma unroll
            for (int j = 0; j < 8; ++j)
                bfrag[t][h2][j] = (short)f2bf(
                    W[(h2 * 32 + quad * 8 + j) * 128 + t * 16 + l16]);

    float atts[8], attd[8];
    #pragma unroll
    for (int t = 0; t < 8; ++t) {
        atts[t] = att_src[t * 16 + l16];
        attd[t] = att_dst[t * 16 + l16];
    }

    const int arow = tb + l16;
    short8_v a0 = (short8_v)0, a1 = (short8_v)0;
    if (arow < N) {
        const float* xr = (arow < n_users)
            ? (users + (size_t)arow * 64)
            : (items + (size_t)(arow - n_users) * 64);
        const float4_v x0 = *reinterpret_cast<const float4_v*>(xr + quad * 8);
        const float4_v x1 = *reinterpret_cast<const float4_v*>(xr + quad * 8 + 4);
        const float4_v x2 = *reinterpret_cast<const float4_v*>(xr + 32 + quad * 8);
        const float4_v x3 = *reinterpret_cast<const float4_v*>(xr + 32 + quad * 8 + 4);
        #pragma unroll
        for (int j = 0; j < 4; ++j) {
            a0[j]     = (short)f2bf(x0[j]);
            a0[j + 4] = (short)f2bf(x1[j]);
            a1[j]     = (short)f2bf(x2[j]);
            a1[j + 4] = (short)f2bf(x3[j]);
        }
    }

    float4_v acc[8];
    #pragma unroll
    for (int t = 0; t < 8; ++t) {
        acc[t] = (float4_v)0.f;
        acc[t] = __builtin_amdgcn_mfma_f32_16x16x32_bf16(a0, bfrag[t][0], acc[t], 0, 0, 0);
        acc[t] = __builtin_amdgcn_mfma_f32_16x16x32_bf16(a1, bfrag[t][1], acc[t], 0, 0, 0);
    }

    const int wrow0 = tb + quad * 4;
    float s0[4] = {0,0,0,0}, s1[4] = {0,0,0,0};
    float d0[4] = {0,0,0,0}, d1[4] = {0,0,0,0};
    #pragma unroll
    for (int t = 0; t < 8; ++t) {
        #pragma unroll
        for (int r = 0; r < 4; ++r) {
            const float v = acc[t][r];
            if (t < 4) { s0[r] = fmaf(v, atts[t], s0[r]);
                         d0[r] = fmaf(v, attd[t], d0[r]); }
            else       { s1[r] = fmaf(v, atts[t], s1[r]);
                         d1[r] = fmaf(v, attd[t], d1[r]); }
            const int row = wrow0 + r;
            if (row < N)
                hb[(size_t)row * 128 + t * 16 + l16] = f2bf(v);
        }
    }

    #pragma unroll
    for (int off = 1; off < 16; off <<= 1) {
        #pragma unroll
        for (int r = 0; r < 4; ++r) {
            s0[r] += __shfl_xor(s0[r], off);
            s1[r] += __shfl_xor(s1[r], off);
            d0[r] += __shfl_xor(d0[r], off);
            d1[r] += __shfl_xor(d1[r], off);
        }
    }
    if (l16 == 0) {
        #pragma unroll
        for (int r = 0; r < 4; ++r) {
            const int row = wrow0 + r;
            if (row < N) {
                a_src[row * 2]     = s0[r];
                a_src[row * 2 + 1] = s1[r];
                a_dst[row * 2]     = d0[r];
                a_dst[row * 2 + 1] = d1[r];
            }
        }
    }
}

// ---------------------------------------------------------------------------
// K2: exclusive scan of bcnt -> bucket_base AND tails. Single wave.
// Also writes rowptr[N] = E.
// ---------------------------------------------------------------------------
__global__ void k_bscan(const int* __restrict__ bcnt,
                        int* __restrict__ bucket_base,
                        int* __restrict__ tails,
                        int* __restrict__ rowptr,
                        int nbuckets, int N, int E)
{
    const int lane = threadIdx.x;          // 64 threads
    int running = 0;
    for (int base = 0; base < nbuckets; base += 64) {
        int idx = base + lane;
        int v = (idx < nbuckets) ? bcnt[idx] : 0;
        int incl = v;
        #pragma unroll
        for (int off = 1; off < 64; off <<= 1) {
            int t = __shfl_up(incl, off);
            if (lane >= off) incl += t;
        }
        if (idx < nbuckets) {
            int ex = running + incl - v;
            bucket_base[idx] = ex;
            tails[idx]       = ex;
        }
        running += __shfl(incl, 63);
    }
    if (lane == 0) rowptr[N] = E;
}

// ---------------------------------------------------------------------------
// K3: bin pass, 512 thr (8 waves — hides a_src/a_dst gather latency).
// Each block: read 2048 edges ONCE, build packed records
//   rec.x = (ex1_h<<16)|ex0_h, rec.y = src | (dst&255)<<17
// LDS counting-sort by bucket, one atomic tail bump per bucket +
// contiguous burst write.
// ---------------------------------------------------------------------------
__global__ void k_bin(const int* __restrict__ src, const int* __restrict__ dst,
                      const float* __restrict__ a_src,
                      const float* __restrict__ a_dst,
                      int* __restrict__ tails,
                      int2* __restrict__ stage_g,
                      int nedges, int nbuckets)
{
    __shared__ int cnt[MAXB];
    __shared__ int runoff[MAXB];
    __shared__ int cursor[MAXB];
    __shared__ int runbase[MAXB];
    __shared__ int2 stage[BIN_E];
    __shared__ unsigned short sb[BIN_E];

    const int tid  = threadIdx.x;          // 0..511
    const int lane = tid & 63;
    const int wid  = tid >> 6;             // 0..7
    const int base = blockIdx.x * BIN_E;
    const int nvalid = min(BIN_E, nedges - base);

    for (int i = tid; i < nbuckets; i += 512) cnt[i] = 0;
    __syncthreads();

    int2 myrec[BIN_E / 512];
    int  myb[BIN_E / 512];
    #pragma unroll
    for (int k = 0; k < BIN_E / 512; ++k) {
        int i = base + k * 512 + tid;
        if (i < nedges) {
            int d = dst[i];
            int s = src[i];
            const float2 as2 = *reinterpret_cast<const float2*>(a_src + 2 * s);
            const float2 ad2 = *reinterpret_cast<const float2*>(a_dst + 2 * d);
            unsigned e0 = f2h_bits(__expf(lrelu(as2.x + ad2.x)));
            unsigned e1 = f2h_bits(__expf(lrelu(as2.y + ad2.y)));
            myrec[k].x = (int)((e1 << 16) | e0);
            myrec[k].y = s | ((d & 255) << 17);
            int b = d >> 8;
            myb[k] = b;
            atomicAdd(&cnt[b], 1);
        } else {
            myb[k] = -1;
        }
    }
    __syncthreads();

    // wave 0: exclusive scan cnt -> runoff
    if (wid == 0) {
        int running = 0;
        for (int b2 = 0; b2 < nbuckets; b2 += 64) {
            int idx = b2 + lane;
            int v = (idx < nbuckets) ? cnt[idx] : 0;
            int incl = v;
            #pragma unroll
            for (int off = 1; off < 64; off <<= 1) {
                int t = __shfl_up(incl, off);
                if (lane >= off) incl += t;
            }
            if (idx < nbuckets) runoff[idx] = running + incl - v;
            running += __shfl(incl, 63);
        }
    }
    __syncthreads();

    for (int i = tid; i < nbuckets; i += 512) cursor[i] = runoff[i];
    __syncthreads();

    #pragma unroll
    for (int k = 0; k < BIN_E / 512; ++k) {
        if (myb[k] >= 0) {
            int pos = atomicAdd(&cursor[myb[k]], 1);
            stage[pos] = myrec[k];
            sb[pos] = (unsigned short)myb[k];
        }
    }

    for (int i = tid; i < nbuckets; i += 512)
        if (cnt[i] > 0) runbase[i] = atomicAdd(&tails[i], cnt[i]);
    __syncthreads();

    for (int i = tid; i < nvalid; i += 512) {
        int b = sb[i];
        stage_g[runbase[b] + (i - runoff[b])] = stage[i];
    }
}

// ---------------------------------------------------------------------------
// K4: refine, 1024 thr (16 waves — the old 256-thr version was 1 block/CU
// with only 4 waves, pure latency-bound). One block per bucket (256 nodes):
// histogram records over 256 node slots (rowptr falls out free), scan,
// scatter into exact per-dst CSR order.
// ---------------------------------------------------------------------------
__global__ void k_refine(const int2* __restrict__ stage_g,
                         const int* __restrict__ bucket_base,
                         int* __restrict__ rowptr,
                         int2* __restrict__ recs,
                         int N, int E, int nbuckets)
{
    const int b   = blockIdx.x;
    const int tid = threadIdx.x;           // 0..1023
    const int lane = tid & 63;
    const int wid  = tid >> 6;
    const int lo = bucket_base[b];
    const int hi = (b + 1 < nbuckets) ? bucket_base[b + 1] : E;
    const int node0  = b << 8;
    const int nnodes = min(256, N - node0);

    __shared__ int cnt[256];
    __shared__ int off[256];
    __shared__ int cursor[256];

    if (tid < 256) cnt[tid] = 0;
    __syncthreads();

    for (int i = lo + tid; i < hi; i += 1024) {
        int dlow = (stage_g[i].y >> 17) & 255;
        atomicAdd(&cnt[dlow], 1);
    }
    __syncthreads();

    if (wid == 0) {
        int running = 0;
        for (int b2 = 0; b2 < 256; b2 += 64) {
            int idx = b2 + lane;
            int v = cnt[idx];
            int incl = v;
            #pragma unroll
            for (int o = 1; o < 64; o <<= 1) {
                int t = __shfl_up(incl, o);
                if (lane >= o) incl += t;
            }
            off[idx] = running + incl - v;
            running += __shfl(incl, 63);
        }
    }
    __syncthreads();

    if (tid < nnodes) rowptr[node0 + tid] = lo + off[tid];
    if (tid < 256) cursor[tid] = lo + off[tid];
    __syncthreads();

    for (int i = lo + tid; i < hi; i += 1024) {
        int2 r = stage_g[i];
        int dlow = (r.y >> 17) & 255;
        int pos = atomicAdd(&cursor[dlow], 1);
        recs[pos] = r;
    }
}

// ---------------------------------------------------------------------------
// K5: gather-accumulate. One wave per node; quarter-wave (16 lanes) per
// edge, 4 edges in flight (+unroll 4 for deeper MLP). Lane sl owns
// channels sl*8..sl*8+7 (ushort8 = 16 B, 256 B coalesced row per quarter).
// Self-loop = virtual edge 0.
// ---------------------------------------------------------------------------
__global__ void k_gather(const int* __restrict__ rowptr,
                         const int2* __restrict__ recs,
                         const float* __restrict__ a_src,
                         const float* __restrict__ a_dst,
                         const unsigned short* __restrict__ hb,
                         const float* __restrict__ bias,
                         float* __restrict__ out,
                         int nnodes)
{
    const int d = blockIdx.x * 4 + (threadIdx.x >> 6);  // wave per node
    if (d >= nnodes) return;
    const int lane = threadIdx.x & 63;
    const int q    = lane >> 4;            // quarter: which edge of the 4
    const int sl   = lane & 15;            // channel group: 8 ch each
    const int hd   = sl >> 3;              // head of those channels

    const float2 as2 = *reinterpret_cast<const float2*>(a_src + 2 * d);
    const float2 ad2 = *reinterpret_cast<const float2*>(a_dst + 2 * d);
    const float exs0 = __expf(lrelu(as2.x + ad2.x));
    const float exs1 = __expf(lrelu(as2.y + ad2.y));

    const int start = rowptr[d];
    const int cnt1  = rowptr[d + 1] - start + 1;   // +1 for self loop

    float acc[8];
    #pragma unroll
    for (int i = 0; i < 8; ++i) acc[i] = 0.f;
    float den = 0.f;

    #pragma unroll 4
    for (int v = q; v < cnt1; v += 4) {
        int s; float ex;
        if (v == 0) {
            s = d;  ex = hd ? exs1 : exs0;
        } else {
            const int2 r = recs[start + v - 1];
            s = r.y & 0x1FFFF;
            const unsigned eb = (unsigned)r.x;
            ex = h2f_bits(hd ? (unsigned short)(eb >> 16)
                             : (unsigned short)(eb & 0xFFFFu));
        }
        const ushort8_v hv = *reinterpret_cast<const ushort8_v*>(
            hb + (size_t)s * 128 + sl * 8);
        den += ex;
        #pragma unroll
        for (int i = 0; i < 8; ++i)
            acc[i] = fmaf(ex, bf2f(hv[i]), acc[i]);
    }

    // merge the four quarter accumulators
    #pragma unroll
    for (int off = 16; off <= 32; off <<= 1) {
        #pragma unroll
        for (int i = 0; i < 8; ++i) acc[i] += __shfl_xor(acc[i], off);
        den += __shfl_xor(den, off);
    }

    if (q == 0) {
        const float inv = 1.f / (den + 1e-16f);
        float4 o0, o1;
        o0.x = acc[0] * inv + bias[sl * 8 + 0];
        o0.y = acc[1] * inv + bias[sl * 8 + 1];
        o0.z = acc[2] * inv + bias[sl * 8 + 2];
        o0.w = acc[3] * inv + bias[sl * 8 + 3];
        o1.x = acc[4] * inv + bias[sl * 8 + 4];
        o1.y = acc[5] * inv + bias[sl * 8 + 5];
        o1.z = acc[6] * inv + bias[sl * 8 + 6];
        o1.w = acc[7] * inv + bias[sl * 8 + 7];
        float* op = out + (size_t)d * 128 + sl * 8;
        *reinterpret_cast<float4*>(op)     = o0;
        *reinterpret_cast<float4*>(op + 4) = o1;
    }
}

extern "C" void kernel_launch(void* const* d_in, const int* in_sizes, int n_in,
                              void* d_out, int out_size, void* d_ws, size_t ws_size,
                              hipStream_t stream) {
    const int*   edge  = (const int*)  d_in[0];   // (2,E) int32
    const float* users = (const float*)d_in[1];   // (N_USERS,64) f32
    const float* items = (const float*)d_in[2];   // (N_ITEMS,64) f32
    const float* W     = (const float*)d_in[3];   // (64,128) f32
    const float* att_s = (const float*)d_in[4];   // (2,64) f32
    const float* att_d = (const float*)d_in[5];   // (2,64) f32
    const float* bias  = (const float*)d_in[6];   // (128,) f32

    const int E       = in_sizes[0] / 2;
    const int n_users = in_sizes[1] / 64;
    const int n_items = in_sizes[2] / 64;
    const int N       = n_users + n_items;
    const int nbuckets = (N + 255) >> 8;          // 259

    float* out = (float*)d_out;

    // Workspace layout (8-B alignment maintained):
    // hb (N*128 bf16) | stage (E int2) | recs (E int2) | a_src | a_dst
    // | rowptr (N+1) | bcnt | bucket_base | tails
    char* ws = (char*)d_ws;
    unsigned short* hb = (unsigned short*)ws;
    ws += (size_t)N * 128 * sizeof(unsigned short);
    int2*  stage    = (int2*)ws;   ws += (size_t)E * sizeof(int2);
    int2*  recs     = (int2*)ws;   ws += (size_t)E * sizeof(int2);
    float* a_src    = (float*)ws;  ws += (size_t)N * 2 * sizeof(float);
    float* a_dst    = (float*)ws;  ws += (size_t)N * 2 * sizeof(float);
    int*   rowptr   = (int*)ws;    ws += (size_t)(N + 1) * sizeof(int);
    int*   bcnt     = (int*)ws;    ws += MAXB * sizeof(int);
    int*   bucket_base = (int*)ws; ws += MAXB * sizeof(int);
    int*   tails    = (int*)ws;

    const int* src = edge;
    const int* dst = edge + E;

    hipMemsetAsync(bcnt, 0, MAXB * sizeof(int), stream);

    const int node_blocks = (N + 63) / 64;
    k_node_hist<<<HIST_BLKS + node_blocks, 256, 0, stream>>>(
        users, items, W, att_s, att_d, hb, a_src, a_dst,
        dst, bcnt, E, nbuckets, n_users, N);

    k_bscan<<<1, 64, 0, stream>>>(bcnt, bucket_base, tails, rowptr,
                                  nbuckets, N, E);

    k_bin<<<(E + BIN_E - 1) / BIN_E, 512, 0, stream>>>(
        src, dst, a_src, a_dst, tails, stage, E, nbuckets);

    k_refine<<<nbuckets, 1024, 0, stream>>>(stage, bucket_base, rowptr,
                                            recs, N, E, nbuckets);

    k_gather<<<(N + 3) / 4, 256, 0, stream>>>(rowptr, recs, a_src, a_dst,
                                              hb, bias, out, N);
}